// Round 1
// baseline (187.400 us; speedup 1.0000x reference)
//
#include <hip/hip_runtime.h>
#include <math.h>
#include <stdint.h>

#define N_NODES 100000
#define N_EDGES 1000000
#define HDIM 128
#define N_NONLOOP (N_EDGES - N_NODES)          // 900000 edges needing atomics

typedef float  vfloat4 __attribute__((ext_vector_type(4)));
typedef int    vint4   __attribute__((ext_vector_type(4)));

__device__ __forceinline__ float get_invtau(const int* __restrict__ training_step) {
    int step = training_step[0];
    float tau;
    if (step == -1) {
        tau = 0.1f;  // TEMP_EVAL
    } else {
        float frac = fminf((float)step / 10000.0f, 1.0f);
        tau = 1.0f + (0.1f - 1.0f) * frac;
    }
    return 1.0f / tau;
}

__device__ __forceinline__ float wave_reduce(float v) {
    #pragma unroll
    for (int off = 32; off > 0; off >>= 1) v += __shfl_down(v, off, 64);
    return v;
}

// ---------------------------------------------------------------------------
// Fused prelude, all independent work in ONE kernel (no internal deps):
//   blocks [0,33):        tabs computed DIRECTLY from params (132 waves).
//                         A[i][h] = invtau * sum_o wd_h[o] * sum_l emb[i][l]*cW[l][o]
//                         (reassociated vs old uv two-stage; same sum).
//   blocks [33,424):      node_pack[n] = {s[n], ns_idx[n]}, acc[n]=0, loss=0.
//   blocks [424,1401):    ei[e] = 4-bit packed edge_states index, 4 edges/thread.
//                         1 MB table -> per-XCD L2 resident for the edge gather.
// ---------------------------------------------------------------------------
#define TAB_BLOCKS  33
#define NODE_BLOCKS 391    // ceil(100000/256)
#define EI_BLOCKS   977    // ceil(250000/256)

__global__ __launch_bounds__(256) void fused_pre(
    const int* __restrict__ node_states,
    const float* __restrict__ s,
    const int* __restrict__ edge_states,
    const float* __restrict__ node_emb,
    const float* __restrict__ edge_emb,
    const float* __restrict__ cW, const float* __restrict__ cb,
    const float* __restrict__ kW, const float* __restrict__ kb,
    const float* __restrict__ pW, const float* __restrict__ pb,
    const float* __restrict__ pnW, const float* __restrict__ pnb,
    const float* __restrict__ iW, const float* __restrict__ ib,
    const int* __restrict__ tstep,
    float2* __restrict__ node_pack,
    float* __restrict__ acc,
    uint8_t* __restrict__ ei,
    float* __restrict__ tabs,
    float* __restrict__ loss_out)
{
    const int b = blockIdx.x;

    if (b < TAB_BLOCKS) {
        // ---- direct table computation: one wave per tab entry ----
        const int w    = b * 4 + (threadIdx.x >> 6);   // 0..131
        const int lane = threadIdx.x & 63;
        if (w >= 132) return;
        const float invtau = get_invtau(tstep);

        if (w < 128) {
            const int isB = w >> 6, h = (w >> 4) & 3, i = w & 15;
            const float* emb = isB ? node_emb : edge_emb;
            const float* cWh = cW + isB * 128 * 128;
            float t0 = 0.f, t1 = 0.f;
            #pragma unroll 4
            for (int l = 0; l < 128; ++l) {
                const float el = emb[i * 128 + l];          // wave-uniform (scalar)
                t0 += el * cWh[l * 128 + lane];
                t1 += el * cWh[l * 128 + 64 + lane];
            }
            const float* W = (h == 0) ? kW : (h == 1) ? pW : (h == 2) ? pnW : iW;
            const float wd0 = W[2 * lane] - W[2 * lane + 1];
            const float wd1 = W[2 * (lane + 64)] - W[2 * (lane + 64) + 1];
            float p = t0 * wd0 + t1 * wd1;
            p = wave_reduce(p);
            if (lane == 0) tabs[isB * 64 + i * 4 + h] = p * invtau;
        } else {
            const int h = w & 3;
            const float* W = (h == 0) ? kW : (h == 1) ? pW : (h == 2) ? pnW : iW;
            const float wd0 = W[2 * lane] - W[2 * lane + 1];
            const float wd1 = W[2 * (lane + 64)] - W[2 * (lane + 64) + 1];
            float p = cb[lane] * wd0 + cb[64 + lane] * wd1;
            p = wave_reduce(p);
            if (lane == 0) {
                const float* bb = (h == 0) ? kb : (h == 1) ? pb : (h == 2) ? pnb : ib;
                tabs[128 + h] = (p + bb[0] - bb[1]) * invtau;
            }
        }
        return;
    }

    if (b < TAB_BLOCKS + NODE_BLOCKS) {
        // ---- node precompute ----
        const int n = (b - TAB_BLOCKS) * 256 + threadIdx.x;
        if (n == 0) *loss_out = 0.f;
        if (n < N_NODES) {
            vint4 st = __builtin_nontemporal_load(&((const vint4*)node_states)[n]);
            const int idx = st.x + 2 * st.y + 4 * st.z + 8 * st.w;
            float2 np;
            np.x = s[n];
            np.y = __int_as_float(idx);
            node_pack[n] = np;
            acc[n] = 0.f;
        }
        return;
    }

    // ---- ei packing: 4 edges/thread, streaming NT reads, uint32 write ----
    const int t = (b - TAB_BLOCKS - NODE_BLOCKS) * 256 + threadIdx.x;
    if (t < N_EDGES / 4) {
        const vint4* esp = (const vint4*)edge_states + 4 * t;
        vint4 e0 = __builtin_nontemporal_load(esp + 0);
        vint4 e1 = __builtin_nontemporal_load(esp + 1);
        vint4 e2 = __builtin_nontemporal_load(esp + 2);
        vint4 e3 = __builtin_nontemporal_load(esp + 3);
        const uint32_t i0 = e0.x + 2 * e0.y + 4 * e0.z + 8 * e0.w;
        const uint32_t i1 = e1.x + 2 * e1.y + 4 * e1.z + 8 * e1.w;
        const uint32_t i2 = e2.x + 2 * e2.y + 4 * e2.z + 8 * e2.w;
        const uint32_t i3 = e3.x + 2 * e3.y + 4 * e3.z + 8 * e3.w;
        ((uint32_t*)ei)[t] = i0 | (i1 << 8) | (i2 << 16) | (i3 << 24);
    }
}

// ---------------------------------------------------------------------------
// Non-loop edges. 4 edges/thread. Key change vs previous version: the loss
// block-reduction barrier now comes BEFORE the acc atomics and the out store,
// so the compiler's vmcnt(0)-before-s_barrier no longer waits on 256 atomic
// acks per wave. Atomics/stores are fire-and-forget; waves retire without
// drain (dispatch-end fence still orders them before finalize_nodes).
// edge_states gather replaced by 1-byte gather from the L2-resident ei table.
// ---------------------------------------------------------------------------
__global__ __launch_bounds__(256) void edge_kernel(
    const float* __restrict__ s,
    const int* __restrict__ src,
    const int* __restrict__ dst,
    const int* __restrict__ brev,
    const uint8_t* __restrict__ ei,
    const float2* __restrict__ node_pack,
    const float* __restrict__ tabs,
    const float* __restrict__ target,
    float* __restrict__ acc,
    float* __restrict__ out,
    float* __restrict__ loss_out)
{
    __shared__ float4 sf[33];  // [0..15] A, [16..31] B, [32] C
    if (threadIdx.x < 33) sf[threadIdx.x] = ((const float4*)tabs)[threadIdx.x];
    __syncthreads();

    const int t = blockIdx.x * blockDim.x + threadIdx.x;   // 0 .. 225023
    const bool active = (t < N_NONLOOP / 4);
    float lsum = 0.f;
    float ov[4], av[4];
    int   dsv[4];
    int   g = 0;

    if (active) {
        g = (N_NODES / 4) + t;  // 16B-aligned quad index
        const vint4   rv = __builtin_nontemporal_load(&((const vint4*)brev)[g]);
        const vint4   sr = __builtin_nontemporal_load(&((const vint4*)src)[g]);
        const vint4   ds = __builtin_nontemporal_load(&((const vint4*)dst)[g]);
        const vfloat4 sv = __builtin_nontemporal_load(&((const vfloat4*)s)[g]);
        const vfloat4 tg = __builtin_nontemporal_load(&((const vfloat4*)target)[g]);

        const int rvv[4] = {rv.x, rv.y, rv.z, rv.w};
        const int srv[4] = {sr.x, sr.y, sr.z, sr.w};
        dsv[0] = ds.x; dsv[1] = ds.y; dsv[2] = ds.z; dsv[3] = ds.w;
        const float svv[4] = {sv.x, sv.y, sv.z, sv.w};
        const float tgv[4] = {tg.x, tg.y, tg.z, tg.w};

        // 12 independent gathers issued up front (all L2-class now)
        int    eidx[4];
        float2 np[4];
        float  sd[4];
        #pragma unroll
        for (int j = 0; j < 4; ++j) {
            eidx[j] = ei[rvv[j]];
            np[j]   = node_pack[srv[j]];
            sd[j]   = node_pack[dsv[j]].x;
        }

        const float4 c4 = sf[32];
        #pragma unroll
        for (int j = 0; j < 4; ++j) {
            const int   ni = __float_as_int(np[j].y);
            const float ss = np[j].x;
            const float4 a = sf[eidx[j]];
            const float4 b = sf[16 + ni];
            const float lk  = a.x + b.x + c4.x;
            const float lp  = a.y + b.y + c4.y;
            const float lpn = a.z + b.z + c4.z;
            const float li  = a.w + b.w + c4.w;
            const float pk  = 1.f / (1.f + __expf(-lk));
            const float pp  = 1.f / (1.f + __expf(-lp));
            const float ppn = 1.f / (1.f + __expf(-lpn));
            const float pi  = 1.f / (1.f + __expf(-li));

            const float s_wo = svv[j] - sd[j];
            const float s_w  = s_wo + ss;
            av[j] = pp * s_wo + ppn * s_w;

            ov[j] = pi + svv[j] * pk;
            const float d = tgv[j] - ov[j];
            lsum += d * d;
        }
    }

    // ---- loss reduction FIRST (vmcnt already drained by the compute) ----
    lsum = wave_reduce(lsum);
    __shared__ float wsum[4];
    const int lane = threadIdx.x & 63, wid = threadIdx.x >> 6;
    if (lane == 0) wsum[wid] = lsum;
    __syncthreads();
    if (threadIdx.x == 0) {
        const float tot = wsum[0] + wsum[1] + wsum[2] + wsum[3];
        atomicAdd(loss_out, tot * (1.0f / (float)N_EDGES));
    }

    // ---- fire-and-forget: atomics + out store, no barrier afterwards ----
    if (active) {
        #pragma unroll
        for (int j = 0; j < 4; ++j)
            unsafeAtomicAdd(&acc[dsv[j]], av[j]);
        vfloat4 o4 = {ov[0], ov[1], ov[2], ov[3]};
        __builtin_nontemporal_store(o4, &((vfloat4*)out)[g]);
    }
}

// ---------------------------------------------------------------------------
// Loop edges (e < N_NODES): src=dst=e so s_wo=0; push contribution ppn*s[e]
// is local (no atomic). out[e] = pi + s[e]*(pk + ppn) + acc[e].
// Same reorder: reduction barrier before the out store.
// ---------------------------------------------------------------------------
__global__ __launch_bounds__(256) void finalize_nodes(
    const int* __restrict__ brev,
    const uint8_t* __restrict__ ei,
    const float2* __restrict__ node_pack,
    const float* __restrict__ tabs,
    const float* __restrict__ target,
    const float* __restrict__ acc,
    float* __restrict__ out,
    float* __restrict__ loss_out)
{
    __shared__ float4 sf[33];
    if (threadIdx.x < 33) sf[threadIdx.x] = ((const float4*)tabs)[threadIdx.x];
    __syncthreads();

    const int n = blockIdx.x * blockDim.x + threadIdx.x;
    const bool active = (n < N_NODES);
    float sq = 0.f, v = 0.f;
    if (active) {
        const int    rev = brev[n];
        const int    eidx = ei[rev];                 // byte gather, L2-resident
        const float2 np  = node_pack[n];
        const int    ni  = __float_as_int(np.y);
        const float  sv  = np.x;

        const float4 a  = sf[eidx];
        const float4 b  = sf[16 + ni];
        const float4 c4 = sf[32];
        const float lk  = a.x + b.x + c4.x;
        const float lpn = a.z + b.z + c4.z;
        const float li  = a.w + b.w + c4.w;
        const float pk  = 1.f / (1.f + __expf(-lk));
        const float ppn = 1.f / (1.f + __expf(-lpn));
        const float pi  = 1.f / (1.f + __expf(-li));

        v = pi + sv * (pk + ppn) + acc[n];
        const float d = target[n] - v;
        sq = d * d;
    }
    sq = wave_reduce(sq);
    __shared__ float wsum[4];
    const int lane = threadIdx.x & 63, wid = threadIdx.x >> 6;
    if (lane == 0) wsum[wid] = sq;
    __syncthreads();
    if (threadIdx.x == 0) {
        const float tot = wsum[0] + wsum[1] + wsum[2] + wsum[3];
        atomicAdd(loss_out, tot * (1.0f / (float)N_EDGES));
    }
    if (active) out[n] = v;
}

extern "C" void kernel_launch(void* const* d_in, const int* in_sizes, int n_in,
                              void* d_out, int out_size, void* d_ws, size_t ws_size,
                              hipStream_t stream) {
    const int*   node_states   = (const int*)d_in[0];
    const int*   edge_states   = (const int*)d_in[1];
    const float* scalars       = (const float*)d_in[2];
    const int*   edge_index    = (const int*)d_in[3];
    const int*   brev          = (const int*)d_in[4];
    const float* batch_scalars = (const float*)d_in[5];
    // d_in[6] = processor_step (batch axis-1 size 1 -> index 0)
    const int*   training_step = (const int*)d_in[7];
    const float* node_emb  = (const float*)d_in[8];
    const float* edge_emb  = (const float*)d_in[9];
    const float* combine_W = (const float*)d_in[10];
    const float* combine_b = (const float*)d_in[11];
    const float* keep_W  = (const float*)d_in[12];
    const float* keep_b  = (const float*)d_in[13];
    const float* push_W  = (const float*)d_in[14];
    const float* push_b  = (const float*)d_in[15];
    const float* pushn_W = (const float*)d_in[16];
    const float* pushn_b = (const float*)d_in[17];
    const float* inc_W   = (const float*)d_in[18];
    const float* inc_b   = (const float*)d_in[19];

    float* out = (float*)d_out;  // [0..E) new_scalars, [E] loss

    char* ws = (char*)d_ws;
    float*   tabs      = (float*)ws;                                  // 132 floats (pad 1 KiB)
    float*   acc       = (float*)(ws + 1024);                         // N floats (400 KB)
    float2*  node_pack = (float2*)(ws + 1024 + (size_t)N_NODES * 4);  // N float2 (800 KB)
    uint8_t* ei        = (uint8_t*)(ws + 1024 + (size_t)N_NODES * 12);// E bytes (1 MB)

    const int* srcp = edge_index;
    const int* dstp = edge_index + N_EDGES;

    fused_pre<<<TAB_BLOCKS + NODE_BLOCKS + EI_BLOCKS, 256, 0, stream>>>(
        node_states, scalars, edge_states, node_emb, edge_emb,
        combine_W, combine_b, keep_W, keep_b, push_W, push_b,
        pushn_W, pushn_b, inc_W, inc_b, training_step,
        node_pack, acc, ei, tabs, out + N_EDGES);

    const int ethreads = N_NONLOOP / 4;   // 225000
    edge_kernel<<<(ethreads + 255) / 256, 256, 0, stream>>>(
        scalars, srcp, dstp, brev, ei, node_pack, tabs, batch_scalars,
        acc, out, out + N_EDGES);

    finalize_nodes<<<(N_NODES + 255) / 256, 256, 0, stream>>>(
        brev, ei, node_pack, tabs, batch_scalars, acc, out, out + N_EDGES);
}

// Round 2
// 179.983 us; speedup vs baseline: 1.0412x; 1.0412x over previous
//
#include <hip/hip_runtime.h>
#include <math.h>
#include <stdint.h>

#define N_NODES 100000
#define N_EDGES 1000000
#define N_NONLOOP (N_EDGES - N_NODES)          // 900000 edges needing atomics
#define NXCD 8

typedef float  vfloat4 __attribute__((ext_vector_type(4)));
typedef int    vint4   __attribute__((ext_vector_type(4)));

// HW_REG_XCC_ID = 20 on gfx940+; read bits [3:0]. imm = id | (off<<6) | ((sz-1)<<11)
#define XCC_ID_HWREG (20 | ((4 - 1) << 11))

__device__ __forceinline__ int get_xcc() {
    return __builtin_amdgcn_s_getreg(XCC_ID_HWREG) & (NXCD - 1);
}

// Plain f32 atomic add with NO coherence bits: performed in the local XCD's
// TCC (L2), no write-through to the device coherence point. Only correct when
// every writer of the target line runs on the SAME XCD (per-XCD copies).
__device__ __forceinline__ void l2_atomic_add(float* p, float v) {
    asm volatile("global_atomic_add_f32 %0, %1, off" :: "v"(p), "v"(v) : "memory");
}

__device__ __forceinline__ float get_invtau(const int* __restrict__ training_step) {
    int step = training_step[0];
    float tau;
    if (step == -1) {
        tau = 0.1f;  // TEMP_EVAL
    } else {
        float frac = fminf((float)step / 10000.0f, 1.0f);
        tau = 1.0f + (0.1f - 1.0f) * frac;
    }
    return 1.0f / tau;
}

__device__ __forceinline__ float wave_reduce(float v) {
    #pragma unroll
    for (int off = 32; off > 0; off >>= 1) v += __shfl_down(v, off, 64);
    return v;
}

// ---------------------------------------------------------------------------
// K1: all independent precompute in one kernel.
//   blocks [0,132):   ONE BLOCK PER TAB ENTRY, 4 waves split the 128-long
//                     contraction (fixes round-1's 128-iter serial chain:
//                     ~14us -> ~3us).
//   next 391 blocks:  node_pack, acc copies zero, lossp zero, eib_node
//                     (= packed edge_states[brev[n]], hoists finalize's
//                     dependent gather chain into this slack kernel).
//   next 977 blocks:  ei[e] 4-bit pack of edge_states (1 MB, L2-class for
//                     the edge gather).
// ---------------------------------------------------------------------------
#define TAB_BLOCKS  132
#define NODE_BLOCKS 391    // ceil(100000/256)
#define EI_BLOCKS   977    // ceil(250000/256)

__global__ __launch_bounds__(256) void fused_pre(
    const int* __restrict__ node_states,
    const float* __restrict__ s,
    const int* __restrict__ edge_states,
    const int* __restrict__ brev,
    const float* __restrict__ node_emb,
    const float* __restrict__ edge_emb,
    const float* __restrict__ cW, const float* __restrict__ cb,
    const float* __restrict__ kW, const float* __restrict__ kb,
    const float* __restrict__ pW, const float* __restrict__ pb,
    const float* __restrict__ pnW, const float* __restrict__ pnb,
    const float* __restrict__ iW, const float* __restrict__ ib,
    const int* __restrict__ tstep,
    float2* __restrict__ node_pack,
    float* __restrict__ acc,
    uint8_t* __restrict__ ei,
    uint8_t* __restrict__ eib_node,
    float* __restrict__ tabs,
    float* __restrict__ lossp,
    float* __restrict__ loss_out,
    int ncopies)
{
    const int b = blockIdx.x;

    if (b < TAB_BLOCKS) {
        // ---- one tab entry per block; wave wv covers l in [wv*32, wv*32+32) ----
        const int w    = b;                       // 0..131
        const int lane = threadIdx.x & 63;
        const int wv   = threadIdx.x >> 6;
        const float invtau = get_invtau(tstep);
        __shared__ float part[4];

        float p = 0.f;
        if (w < 128) {
            const int isB = w >> 6, h = (w >> 4) & 3, i = w & 15;
            const float* emb = isB ? node_emb : edge_emb;
            const float* cWh = cW + isB * 128 * 128;
            float t0 = 0.f, t1 = 0.f;
            const int l0 = wv * 32;
            #pragma unroll 8
            for (int l = l0; l < l0 + 32; ++l) {
                const float el = emb[i * 128 + l];          // wave-uniform (scalar)
                t0 += el * cWh[l * 128 + lane];
                t1 += el * cWh[l * 128 + 64 + lane];
            }
            const float* W = (h == 0) ? kW : (h == 1) ? pW : (h == 2) ? pnW : iW;
            const float wd0 = W[2 * lane] - W[2 * lane + 1];
            const float wd1 = W[2 * (lane + 64)] - W[2 * (lane + 64) + 1];
            p = t0 * wd0 + t1 * wd1;
        } else if (wv == 0) {
            const int h = w & 3;
            const float* W = (h == 0) ? kW : (h == 1) ? pW : (h == 2) ? pnW : iW;
            const float wd0 = W[2 * lane] - W[2 * lane + 1];
            const float wd1 = W[2 * (lane + 64)] - W[2 * (lane + 64) + 1];
            p = cb[lane] * wd0 + cb[64 + lane] * wd1;
        }
        p = wave_reduce(p);
        if (lane == 0) part[wv] = p;
        __syncthreads();
        if (threadIdx.x == 0) {
            const float tot = part[0] + part[1] + part[2] + part[3];
            if (w < 128) {
                const int isB = w >> 6, h = (w >> 4) & 3, i = w & 15;
                tabs[isB * 64 + i * 4 + h] = tot * invtau;
            } else {
                const int h = w & 3;
                const float* bb = (h == 0) ? kb : (h == 1) ? pb : (h == 2) ? pnb : ib;
                tabs[128 + h] = (tot + bb[0] - bb[1]) * invtau;
            }
        }
        return;
    }

    if (b < TAB_BLOCKS + NODE_BLOCKS) {
        // ---- node precompute ----
        const int n = (b - TAB_BLOCKS) * 256 + threadIdx.x;
        if (n < 256) lossp[n] = 0.f;
        if (n == 0) *loss_out = 0.f;
        if (n < N_NODES) {
            vint4 st = __builtin_nontemporal_load(&((const vint4*)node_states)[n]);
            const int idx = st.x + 2 * st.y + 4 * st.z + 8 * st.w;
            float2 np;
            np.x = s[n];
            np.y = __int_as_float(idx);
            node_pack[n] = np;
            for (int k = 0; k < ncopies; ++k) acc[(size_t)k * N_NODES + n] = 0.f;
            // finalize's edge-state index, precomputed (independent gather)
            const int rev = brev[n];
            const int4 est = ((const int4*)edge_states)[rev];
            eib_node[n] = (uint8_t)(est.x + 2 * est.y + 4 * est.z + 8 * est.w);
        }
        return;
    }

    // ---- ei packing: 4 edges/thread, streaming NT reads, uint32 write ----
    const int t = (b - TAB_BLOCKS - NODE_BLOCKS) * 256 + threadIdx.x;
    if (t < N_EDGES / 4) {
        const vint4* esp = (const vint4*)edge_states + 4 * t;
        vint4 e0 = __builtin_nontemporal_load(esp + 0);
        vint4 e1 = __builtin_nontemporal_load(esp + 1);
        vint4 e2 = __builtin_nontemporal_load(esp + 2);
        vint4 e3 = __builtin_nontemporal_load(esp + 3);
        const uint32_t i0 = e0.x + 2 * e0.y + 4 * e0.z + 8 * e0.w;
        const uint32_t i1 = e1.x + 2 * e1.y + 4 * e1.z + 8 * e1.w;
        const uint32_t i2 = e2.x + 2 * e2.y + 4 * e2.z + 8 * e2.w;
        const uint32_t i3 = e3.x + 2 * e3.y + 4 * e3.z + 8 * e3.w;
        ((uint32_t*)ei)[t] = i0 | (i1 << 8) | (i2 << 16) | (i3 << 24);
    }
}

// ---------------------------------------------------------------------------
// Non-loop edges. MODE 1: per-XCD accumulator copies + L2-local (no-sc-bit)
// atomics -- removes the 900K 32B write-throughs to the device coherence
// point that round-1 counters identified as the floor (WRITE_SIZE 31.6MB,
// dur invariant under -43MB FETCH). MODE 0: legacy device-scope fallback.
// ---------------------------------------------------------------------------
template<int MODE>
__global__ __launch_bounds__(256) void edge_kernel(
    const float* __restrict__ s,
    const int* __restrict__ src,
    const int* __restrict__ dst,
    const int* __restrict__ brev,
    const uint8_t* __restrict__ ei,
    const float2* __restrict__ node_pack,
    const float* __restrict__ tabs,
    const float* __restrict__ target,
    float* __restrict__ acc,
    float* __restrict__ lossp,
    float* __restrict__ out,
    float* __restrict__ loss_out)
{
    __shared__ float4 sf[33];  // [0..15] A, [16..31] B, [32] C
    if (threadIdx.x < 33) sf[threadIdx.x] = ((const float4*)tabs)[threadIdx.x];
    __syncthreads();

    int xcc = 0;
    float* accx = acc;
    if (MODE == 1) {
        xcc  = get_xcc();                       // wave-uniform SGPR read
        accx = acc + (size_t)xcc * N_NODES;     // this XCD's private copy
    }

    const int t = blockIdx.x * blockDim.x + threadIdx.x;   // 0 .. 225023
    const bool active = (t < N_NONLOOP / 4);
    float lsum = 0.f;
    float ov[4], av[4];
    int   dsv[4];
    int   g = 0;

    if (active) {
        g = (N_NODES / 4) + t;  // 16B-aligned quad index
        const vint4   rv = __builtin_nontemporal_load(&((const vint4*)brev)[g]);
        const vint4   sr = __builtin_nontemporal_load(&((const vint4*)src)[g]);
        const vint4   ds = __builtin_nontemporal_load(&((const vint4*)dst)[g]);
        const vfloat4 sv = __builtin_nontemporal_load(&((const vfloat4*)s)[g]);
        const vfloat4 tg = __builtin_nontemporal_load(&((const vfloat4*)target)[g]);

        const int rvv[4] = {rv.x, rv.y, rv.z, rv.w};
        const int srv[4] = {sr.x, sr.y, sr.z, sr.w};
        dsv[0] = ds.x; dsv[1] = ds.y; dsv[2] = ds.z; dsv[3] = ds.w;
        const float svv[4] = {sv.x, sv.y, sv.z, sv.w};
        const float tgv[4] = {tg.x, tg.y, tg.z, tg.w};

        int    eidx[4];
        float2 np[4];
        float  sd[4];
        #pragma unroll
        for (int j = 0; j < 4; ++j) {
            eidx[j] = ei[rvv[j]];
            np[j]   = node_pack[srv[j]];
            sd[j]   = node_pack[dsv[j]].x;
        }

        const float4 c4 = sf[32];
        #pragma unroll
        for (int j = 0; j < 4; ++j) {
            const int   ni = __float_as_int(np[j].y);
            const float ss = np[j].x;
            const float4 a = sf[eidx[j]];
            const float4 b = sf[16 + ni];
            const float lk  = a.x + b.x + c4.x;
            const float lp  = a.y + b.y + c4.y;
            const float lpn = a.z + b.z + c4.z;
            const float li  = a.w + b.w + c4.w;
            const float pk  = 1.f / (1.f + __expf(-lk));
            const float pp  = 1.f / (1.f + __expf(-lp));
            const float ppn = 1.f / (1.f + __expf(-lpn));
            const float pi  = 1.f / (1.f + __expf(-li));

            const float s_wo = svv[j] - sd[j];
            const float s_w  = s_wo + ss;
            av[j] = pp * s_wo + ppn * s_w;

            ov[j] = pi + svv[j] * pk;
            const float d = tgv[j] - ov[j];
            lsum += d * d;
        }
    }

    // ---- loss reduction first (vmcnt already drained by the compute) ----
    lsum = wave_reduce(lsum);
    __shared__ float wsum[4];
    const int lane = threadIdx.x & 63, wid = threadIdx.x >> 6;
    if (lane == 0) wsum[wid] = lsum;
    __syncthreads();
    if (threadIdx.x == 0) {
        const float tot = (wsum[0] + wsum[1] + wsum[2] + wsum[3]) * (1.0f / (float)N_EDGES);
        if (MODE == 1) l2_atomic_add(&lossp[xcc * 32], tot);   // 128B-strided cells
        else           atomicAdd(loss_out, tot);
    }

    // ---- fire-and-forget atomics + out store ----
    if (active) {
        #pragma unroll
        for (int j = 0; j < 4; ++j) {
            if (MODE == 1) l2_atomic_add(&accx[dsv[j]], av[j]);
            else           unsafeAtomicAdd(&acc[dsv[j]], av[j]);
        }
        vfloat4 o4 = {ov[0], ov[1], ov[2], ov[3]};
        __builtin_nontemporal_store(o4, &((vfloat4*)out)[g]);
    }
}

// ---------------------------------------------------------------------------
// Loop edges: out[n] = pi + s[n]*(pk+ppn) + sum_k acc[k*N+n].
// eib_node precomputed in K1 (no dependent brev->ei gather chain here).
// Block 0 folds the per-XCD loss cells into loss_out.
// ---------------------------------------------------------------------------
template<int NC>
__global__ __launch_bounds__(256) void finalize_nodes(
    const uint8_t* __restrict__ eib_node,
    const float2* __restrict__ node_pack,
    const float* __restrict__ tabs,
    const float* __restrict__ target,
    const float* __restrict__ acc,
    const float* __restrict__ lossp,
    float* __restrict__ out,
    float* __restrict__ loss_out)
{
    __shared__ float4 sf[33];
    if (threadIdx.x < 33) sf[threadIdx.x] = ((const float4*)tabs)[threadIdx.x];
    __syncthreads();

    const int n = blockIdx.x * blockDim.x + threadIdx.x;
    const bool active = (n < N_NODES);
    float sq = 0.f, v = 0.f;
    if (active) {
        const int    eidx = eib_node[n];
        const float2 np  = node_pack[n];
        const int    ni  = __float_as_int(np.y);
        const float  sv  = np.x;

        float a8 = 0.f;
        #pragma unroll
        for (int k = 0; k < NC; ++k) a8 += acc[(size_t)k * N_NODES + n];

        const float4 a  = sf[eidx];
        const float4 b  = sf[16 + ni];
        const float4 c4 = sf[32];
        const float lk  = a.x + b.x + c4.x;
        const float lpn = a.z + b.z + c4.z;
        const float li  = a.w + b.w + c4.w;
        const float pk  = 1.f / (1.f + __expf(-lk));
        const float ppn = 1.f / (1.f + __expf(-lpn));
        const float pi  = 1.f / (1.f + __expf(-li));

        v = pi + sv * (pk + ppn) + a8;
        const float d = target[n] - v;
        sq = d * d;
    }
    sq = wave_reduce(sq);
    __shared__ float wsum[4];
    const int lane = threadIdx.x & 63, wid = threadIdx.x >> 6;
    if (lane == 0) wsum[wid] = sq;
    __syncthreads();
    if (threadIdx.x == 0) {
        float tot = (wsum[0] + wsum[1] + wsum[2] + wsum[3]) * (1.0f / (float)N_EDGES);
        if (blockIdx.x == 0) {
            // fold per-XCD edge-loss cells (zero in fallback mode)
            #pragma unroll
            for (int k = 0; k < NXCD; ++k) tot += lossp[k * 32];
        }
        atomicAdd(loss_out, tot);
    }
    if (active) out[n] = v;
}

extern "C" void kernel_launch(void* const* d_in, const int* in_sizes, int n_in,
                              void* d_out, int out_size, void* d_ws, size_t ws_size,
                              hipStream_t stream) {
    const int*   node_states   = (const int*)d_in[0];
    const int*   edge_states   = (const int*)d_in[1];
    const float* scalars       = (const float*)d_in[2];
    const int*   edge_index    = (const int*)d_in[3];
    const int*   brev          = (const int*)d_in[4];
    const float* batch_scalars = (const float*)d_in[5];
    // d_in[6] = processor_step (batch axis-1 size 1 -> index 0)
    const int*   training_step = (const int*)d_in[7];
    const float* node_emb  = (const float*)d_in[8];
    const float* edge_emb  = (const float*)d_in[9];
    const float* combine_W = (const float*)d_in[10];
    const float* combine_b = (const float*)d_in[11];
    const float* keep_W  = (const float*)d_in[12];
    const float* keep_b  = (const float*)d_in[13];
    const float* push_W  = (const float*)d_in[14];
    const float* push_b  = (const float*)d_in[15];
    const float* pushn_W = (const float*)d_in[16];
    const float* pushn_b = (const float*)d_in[17];
    const float* inc_W   = (const float*)d_in[18];
    const float* inc_b   = (const float*)d_in[19];

    float* out = (float*)d_out;  // [0..E) new_scalars, [E] loss

    // workspace layout
    const size_t need_scoped = 2048 + (size_t)NXCD * N_NODES * 4 + (size_t)N_NODES * 8
                             + N_EDGES + N_NODES + 1024;
    const bool scoped = (ws_size >= need_scoped);
    const int nc = scoped ? NXCD : 1;

    char* ws = (char*)d_ws;
    float*   tabs      = (float*)ws;                                  // 132 floats (pad 1 KiB)
    float*   lossp     = (float*)(ws + 1024);                         // 8 cells x 128B (pad 1 KiB)
    float*   acc       = (float*)(ws + 2048);                         // nc * N floats
    float2*  node_pack = (float2*)(ws + 2048 + (size_t)nc * N_NODES * 4);
    uint8_t* ei        = (uint8_t*)node_pack + (size_t)N_NODES * 8;   // E bytes
    uint8_t* eib_node  = ei + N_EDGES;                                // N bytes

    const int* srcp = edge_index;
    const int* dstp = edge_index + N_EDGES;

    fused_pre<<<TAB_BLOCKS + NODE_BLOCKS + EI_BLOCKS, 256, 0, stream>>>(
        node_states, scalars, edge_states, brev, node_emb, edge_emb,
        combine_W, combine_b, keep_W, keep_b, push_W, push_b,
        pushn_W, pushn_b, inc_W, inc_b, training_step,
        node_pack, acc, ei, eib_node, tabs, lossp, out + N_EDGES, nc);

    const int ethreads = N_NONLOOP / 4;   // 225000
    const int eblocks  = (ethreads + 255) / 256;
    if (scoped) {
        edge_kernel<1><<<eblocks, 256, 0, stream>>>(
            scalars, srcp, dstp, brev, ei, node_pack, tabs, batch_scalars,
            acc, lossp, out, out + N_EDGES);
        finalize_nodes<NXCD><<<(N_NODES + 255) / 256, 256, 0, stream>>>(
            eib_node, node_pack, tabs, batch_scalars, acc, lossp, out, out + N_EDGES);
    } else {
        edge_kernel<0><<<eblocks, 256, 0, stream>>>(
            scalars, srcp, dstp, brev, ei, node_pack, tabs, batch_scalars,
            acc, lossp, out, out + N_EDGES);
        finalize_nodes<1><<<(N_NODES + 255) / 256, 256, 0, stream>>>(
            eib_node, node_pack, tabs, batch_scalars, acc, lossp, out, out + N_EDGES);
    }
}

// Round 3
// 174.563 us; speedup vs baseline: 1.0735x; 1.0310x over previous
//
#include <hip/hip_runtime.h>
#include <math.h>
#include <stdint.h>

#define N_NODES 100000
#define N_EDGES 1000000
#define N_NONLOOP (N_EDGES - N_NODES)          // 900000 edges needing atomics
#define NXCD 8

// Q20 fixed-point for the accumulator: resolution 2^-20 ~ 9.5e-7,
// range +-2048 (per-node sums are O(10-100) worst case).
#define ACC_SCALE   1048576.0f      // 2^20
#define ACC_INV     (1.0f / 1048576.0f)

typedef float  vfloat4 __attribute__((ext_vector_type(4)));
typedef int    vint4   __attribute__((ext_vector_type(4)));

// HW_REG_XCC_ID = 20 on gfx940+; read bits [3:0]. imm = id | (off<<6) | ((sz-1)<<11)
#define XCC_ID_HWREG (20 | ((4 - 1) << 11))

__device__ __forceinline__ int get_xcc() {
    return __builtin_amdgcn_s_getreg(XCC_ID_HWREG) & (NXCD - 1);
}

// Flag-less u32 atomic add: lowest scope -> executed in the local XCD's TCC
// (integer atomic ALU), line stays dirty in L2, written back at dispatch end.
// Correct ONLY because each acc copy is touched by exactly one XCD.
__device__ __forceinline__ void l2_atomic_add_u32(uint32_t* p, uint32_t v) {
    asm volatile("global_atomic_add %0, %1, off" :: "v"(p), "v"(v) : "memory");
}
__device__ __forceinline__ void l2_atomic_add_f32(float* p, float v) {
    asm volatile("global_atomic_add_f32 %0, %1, off" :: "v"(p), "v"(v) : "memory");
}

__device__ __forceinline__ float get_invtau(const int* __restrict__ training_step) {
    int step = training_step[0];
    float tau;
    if (step == -1) {
        tau = 0.1f;  // TEMP_EVAL
    } else {
        float frac = fminf((float)step / 10000.0f, 1.0f);
        tau = 1.0f + (0.1f - 1.0f) * frac;
    }
    return 1.0f / tau;
}

__device__ __forceinline__ float wave_reduce(float v) {
    #pragma unroll
    for (int off = 32; off > 0; off >>= 1) v += __shfl_down(v, off, 64);
    return v;
}

// ---------------------------------------------------------------------------
// K1: all independent precompute.
//   blocks [0,132):   tabs, one block/entry, 4-wave K-split.
//   next 391 blocks:  nib[n] = packed node_states, acc copies zero, lossp/loss.
//   next 977 blocks:  ei[e] = packed edge_states (1 MB, L2-class gather table).
// ---------------------------------------------------------------------------
#define TAB_BLOCKS  132
#define NODE_BLOCKS 391    // ceil(100000/256)
#define EI_BLOCKS   977    // ceil(250000/256)

__global__ __launch_bounds__(256) void fused_pre(
    const int* __restrict__ node_states,
    const int* __restrict__ edge_states,
    const float* __restrict__ node_emb,
    const float* __restrict__ edge_emb,
    const float* __restrict__ cW, const float* __restrict__ cb,
    const float* __restrict__ kW, const float* __restrict__ kb,
    const float* __restrict__ pW, const float* __restrict__ pb,
    const float* __restrict__ pnW, const float* __restrict__ pnb,
    const float* __restrict__ iW, const float* __restrict__ ib,
    const int* __restrict__ tstep,
    uint32_t* __restrict__ acc,
    uint8_t* __restrict__ ei,
    uint8_t* __restrict__ nib,
    float* __restrict__ tabs,
    float* __restrict__ lossp,
    float* __restrict__ loss_out,
    int ncopies)
{
    const int b = blockIdx.x;

    if (b < TAB_BLOCKS) {
        const int w    = b;                       // 0..131
        const int lane = threadIdx.x & 63;
        const int wv   = threadIdx.x >> 6;
        const float invtau = get_invtau(tstep);
        __shared__ float part[4];

        float p = 0.f;
        if (w < 128) {
            const int isB = w >> 6, h = (w >> 4) & 3, i = w & 15;
            const float* emb = isB ? node_emb : edge_emb;
            const float* cWh = cW + isB * 128 * 128;
            float t0 = 0.f, t1 = 0.f;
            const int l0 = wv * 32;
            #pragma unroll 8
            for (int l = l0; l < l0 + 32; ++l) {
                const float el = emb[i * 128 + l];          // wave-uniform
                t0 += el * cWh[l * 128 + lane];
                t1 += el * cWh[l * 128 + 64 + lane];
            }
            const float* W = (h == 0) ? kW : (h == 1) ? pW : (h == 2) ? pnW : iW;
            const float wd0 = W[2 * lane] - W[2 * lane + 1];
            const float wd1 = W[2 * (lane + 64)] - W[2 * (lane + 64) + 1];
            p = t0 * wd0 + t1 * wd1;
        } else if (wv == 0) {
            const int h = w & 3;
            const float* W = (h == 0) ? kW : (h == 1) ? pW : (h == 2) ? pnW : iW;
            const float wd0 = W[2 * lane] - W[2 * lane + 1];
            const float wd1 = W[2 * (lane + 64)] - W[2 * (lane + 64) + 1];
            p = cb[lane] * wd0 + cb[64 + lane] * wd1;
        }
        p = wave_reduce(p);
        if (lane == 0) part[wv] = p;
        __syncthreads();
        if (threadIdx.x == 0) {
            const float tot = part[0] + part[1] + part[2] + part[3];
            if (w < 128) {
                const int isB = w >> 6, h = (w >> 4) & 3, i = w & 15;
                tabs[isB * 64 + i * 4 + h] = tot * invtau;
            } else {
                const int h = w & 3;
                const float* bb = (h == 0) ? kb : (h == 1) ? pb : (h == 2) ? pnb : ib;
                tabs[128 + h] = (tot + bb[0] - bb[1]) * invtau;
            }
        }
        return;
    }

    if (b < TAB_BLOCKS + NODE_BLOCKS) {
        const int n = (b - TAB_BLOCKS) * 256 + threadIdx.x;
        if (n < 256) lossp[n] = 0.f;
        if (n == 0) *loss_out = 0.f;
        if (n < N_NODES) {
            vint4 st = __builtin_nontemporal_load(&((const vint4*)node_states)[n]);
            nib[n] = (uint8_t)(st.x + 2 * st.y + 4 * st.z + 8 * st.w);
            for (int k = 0; k < ncopies; ++k) acc[(size_t)k * N_NODES + n] = 0u;
        }
        return;
    }

    // ---- ei packing: 4 edges/thread, streaming NT reads, uint32 write ----
    const int t = (b - TAB_BLOCKS - NODE_BLOCKS) * 256 + threadIdx.x;
    if (t < N_EDGES / 4) {
        const vint4* esp = (const vint4*)edge_states + 4 * t;
        vint4 e0 = __builtin_nontemporal_load(esp + 0);
        vint4 e1 = __builtin_nontemporal_load(esp + 1);
        vint4 e2 = __builtin_nontemporal_load(esp + 2);
        vint4 e3 = __builtin_nontemporal_load(esp + 3);
        const uint32_t i0 = e0.x + 2 * e0.y + 4 * e0.z + 8 * e0.w;
        const uint32_t i1 = e1.x + 2 * e1.y + 4 * e1.z + 8 * e1.w;
        const uint32_t i2 = e2.x + 2 * e2.y + 4 * e2.z + 8 * e2.w;
        const uint32_t i3 = e3.x + 2 * e3.y + 4 * e3.z + 8 * e3.w;
        ((uint32_t*)ei)[t] = i0 | (i1 << 8) | (i2 << 16) | (i3 << 24);
    }
}

// ---------------------------------------------------------------------------
// Non-loop edges.
//   MODE 1: per-XCD u32 fixed-point accumulators, flag-less (TCC-local)
//           atomics. LDS block padded to 2560B as a rocprof fingerprint.
//   MODE 0: single acc copy, device-scope u32 atomicAdd. LDS 1024B.
// ---------------------------------------------------------------------------
template<int MODE>
__global__ __launch_bounds__(256) void edge_kernel(
    const float* __restrict__ s,
    const int* __restrict__ src,
    const int* __restrict__ dst,
    const int* __restrict__ brev,
    const uint8_t* __restrict__ ei,
    const uint8_t* __restrict__ nib,
    const float* __restrict__ tabs,
    const float* __restrict__ target,
    uint32_t* __restrict__ acc,
    float* __restrict__ lossp,
    float* __restrict__ out,
    float* __restrict__ loss_out)
{
    __shared__ float4 sf[MODE ? 160 : 33];  // [0..15] A, [16..31] B, [32] C (+pad = fingerprint)
    if (threadIdx.x < 33) sf[threadIdx.x] = ((const float4*)tabs)[threadIdx.x];
    __syncthreads();

    int xcc = 0;
    uint32_t* accx = acc;
    if (MODE == 1) {
        xcc  = get_xcc();                          // wave-uniform SGPR read
        accx = acc + (size_t)xcc * N_NODES;        // this XCD's private copy
    }

    const int t = blockIdx.x * blockDim.x + threadIdx.x;   // 0 .. 225023
    const bool active = (t < N_NONLOOP / 4);
    float lsum = 0.f;
    float ov[4];
    int   iv[4];
    int   dsv[4];
    int   g = 0;

    if (active) {
        g = (N_NODES / 4) + t;  // 16B-aligned quad index
        const vint4   rv = __builtin_nontemporal_load(&((const vint4*)brev)[g]);
        const vint4   sr = __builtin_nontemporal_load(&((const vint4*)src)[g]);
        const vint4   ds = __builtin_nontemporal_load(&((const vint4*)dst)[g]);
        const vfloat4 sv = __builtin_nontemporal_load(&((const vfloat4*)s)[g]);
        const vfloat4 tg = __builtin_nontemporal_load(&((const vfloat4*)target)[g]);

        const int rvv[4] = {rv.x, rv.y, rv.z, rv.w};
        const int srv[4] = {sr.x, sr.y, sr.z, sr.w};
        dsv[0] = ds.x; dsv[1] = ds.y; dsv[2] = ds.z; dsv[3] = ds.w;
        const float svv[4] = {sv.x, sv.y, sv.z, sv.w};
        const float tgv[4] = {tg.x, tg.y, tg.z, tg.w};

        // 16 independent L2-class gathers issued up front
        int   eidx[4], ni[4];
        float ss[4], sd[4];
        #pragma unroll
        for (int j = 0; j < 4; ++j) {
            eidx[j] = ei[rvv[j]];
            ni[j]   = nib[srv[j]];
            ss[j]   = s[srv[j]];
            sd[j]   = s[dsv[j]];
        }

        const float4 c4 = sf[32];
        #pragma unroll
        for (int j = 0; j < 4; ++j) {
            const float4 a = sf[eidx[j]];
            const float4 b = sf[16 + ni[j]];
            const float lk  = a.x + b.x + c4.x;
            const float lp  = a.y + b.y + c4.y;
            const float lpn = a.z + b.z + c4.z;
            const float li  = a.w + b.w + c4.w;
            const float pk  = 1.f / (1.f + __expf(-lk));
            const float pp  = 1.f / (1.f + __expf(-lp));
            const float ppn = 1.f / (1.f + __expf(-lpn));
            const float pi  = 1.f / (1.f + __expf(-li));

            const float s_wo = svv[j] - sd[j];
            const float s_w  = s_wo + ss[j];
            iv[j] = __float2int_rn((pp * s_wo + ppn * s_w) * ACC_SCALE);

            ov[j] = pi + svv[j] * pk;
            const float d = tgv[j] - ov[j];
            lsum += d * d;
        }
    }

    // ---- loss reduction first ----
    lsum = wave_reduce(lsum);
    __shared__ float wsum[4];
    const int lane = threadIdx.x & 63, wid = threadIdx.x >> 6;
    if (lane == 0) wsum[wid] = lsum;
    __syncthreads();
    if (threadIdx.x == 0) {
        const float tot = (wsum[0] + wsum[1] + wsum[2] + wsum[3]) * (1.0f / (float)N_EDGES);
        if (MODE == 1) l2_atomic_add_f32(&lossp[xcc * 32], tot);   // 128B-strided cells
        else           atomicAdd(loss_out, tot);
    }

    // ---- fire-and-forget atomics + out store ----
    if (active) {
        #pragma unroll
        for (int j = 0; j < 4; ++j) {
            if (MODE == 1) l2_atomic_add_u32(&accx[dsv[j]], (uint32_t)iv[j]);
            else           atomicAdd((unsigned int*)&acc[dsv[j]], (unsigned int)iv[j]);
        }
        vfloat4 o4 = {ov[0], ov[1], ov[2], ov[3]};
        __builtin_nontemporal_store(o4, &((vfloat4*)out)[g]);
    }
}

// ---------------------------------------------------------------------------
// Loop edges: out[n] = pi + s[n]*(pk+ppn) + (int)(sum_k acc[k*N+n]) * 2^-20.
// Block 0 folds the per-XCD loss cells.
// ---------------------------------------------------------------------------
template<int NC>
__global__ __launch_bounds__(256) void finalize_nodes(
    const float* __restrict__ s,
    const int* __restrict__ brev,
    const uint8_t* __restrict__ ei,
    const uint8_t* __restrict__ nib,
    const float* __restrict__ tabs,
    const float* __restrict__ target,
    const uint32_t* __restrict__ acc,
    const float* __restrict__ lossp,
    float* __restrict__ out,
    float* __restrict__ loss_out)
{
    __shared__ float4 sf[33];
    if (threadIdx.x < 33) sf[threadIdx.x] = ((const float4*)tabs)[threadIdx.x];
    __syncthreads();

    const int n = blockIdx.x * blockDim.x + threadIdx.x;
    const bool active = (n < N_NODES);
    float sq = 0.f, v = 0.f;
    if (active) {
        const int  eidx = ei[brev[n]];       // L2-hot 1MB table
        const int  ni   = nib[n];
        const float sv  = s[n];

        uint32_t asum = 0u;
        #pragma unroll
        for (int k = 0; k < NC; ++k) asum += acc[(size_t)k * N_NODES + n];
        const float a8 = (float)(int)asum * ACC_INV;

        const float4 a  = sf[eidx];
        const float4 b  = sf[16 + ni];
        const float4 c4 = sf[32];
        const float lk  = a.x + b.x + c4.x;
        const float lpn = a.z + b.z + c4.z;
        const float li  = a.w + b.w + c4.w;
        const float pk  = 1.f / (1.f + __expf(-lk));
        const float ppn = 1.f / (1.f + __expf(-lpn));
        const float pi  = 1.f / (1.f + __expf(-li));

        v = pi + sv * (pk + ppn) + a8;
        const float d = target[n] - v;
        sq = d * d;
    }
    sq = wave_reduce(sq);
    __shared__ float wsum[4];
    const int lane = threadIdx.x & 63, wid = threadIdx.x >> 6;
    if (lane == 0) wsum[wid] = sq;
    __syncthreads();
    if (threadIdx.x == 0) {
        float tot = (wsum[0] + wsum[1] + wsum[2] + wsum[3]) * (1.0f / (float)N_EDGES);
        if (blockIdx.x == 0) {
            #pragma unroll
            for (int k = 0; k < NXCD; ++k) tot += lossp[k * 32];
        }
        atomicAdd(loss_out, tot);
    }
    if (active) out[n] = v;
}

extern "C" void kernel_launch(void* const* d_in, const int* in_sizes, int n_in,
                              void* d_out, int out_size, void* d_ws, size_t ws_size,
                              hipStream_t stream) {
    const int*   node_states   = (const int*)d_in[0];
    const int*   edge_states   = (const int*)d_in[1];
    const float* scalars       = (const float*)d_in[2];
    const int*   edge_index    = (const int*)d_in[3];
    const int*   brev          = (const int*)d_in[4];
    const float* batch_scalars = (const float*)d_in[5];
    // d_in[6] = processor_step (batch axis-1 size 1 -> index 0)
    const int*   training_step = (const int*)d_in[7];
    const float* node_emb  = (const float*)d_in[8];
    const float* edge_emb  = (const float*)d_in[9];
    const float* combine_W = (const float*)d_in[10];
    const float* combine_b = (const float*)d_in[11];
    const float* keep_W  = (const float*)d_in[12];
    const float* keep_b  = (const float*)d_in[13];
    const float* push_W  = (const float*)d_in[14];
    const float* push_b  = (const float*)d_in[15];
    const float* pushn_W = (const float*)d_in[16];
    const float* pushn_b = (const float*)d_in[17];
    const float* inc_W   = (const float*)d_in[18];
    const float* inc_b   = (const float*)d_in[19];

    float* out = (float*)d_out;  // [0..E) new_scalars, [E] loss

    // workspace layout (4-byte types, all 64B-aligned: 400000 % 64 == 0)
    const size_t need_scoped = 2048 + (size_t)NXCD * N_NODES * 4 + N_EDGES + N_NODES;
    const bool scoped = (ws_size >= need_scoped);   // 4,302,048 B
    const int nc = scoped ? NXCD : 1;

    char* ws = (char*)d_ws;
    float*    tabs  = (float*)ws;                                   // 132 floats (pad 1 KiB)
    float*    lossp = (float*)(ws + 1024);                          // 8 cells x 128B (pad 1 KiB)
    uint32_t* acc   = (uint32_t*)(ws + 2048);                       // nc * N u32
    uint8_t*  ei    = (uint8_t*)(ws + 2048 + (size_t)nc * N_NODES * 4);  // E bytes
    uint8_t*  nib   = ei + N_EDGES;                                 // N bytes

    const int* srcp = edge_index;
    const int* dstp = edge_index + N_EDGES;

    fused_pre<<<TAB_BLOCKS + NODE_BLOCKS + EI_BLOCKS, 256, 0, stream>>>(
        node_states, edge_states, node_emb, edge_emb,
        combine_W, combine_b, keep_W, keep_b, push_W, push_b,
        pushn_W, pushn_b, inc_W, inc_b, training_step,
        acc, ei, nib, tabs, lossp, out + N_EDGES, nc);

    const int ethreads = N_NONLOOP / 4;   // 225000
    const int eblocks  = (ethreads + 255) / 256;
    if (scoped) {
        edge_kernel<1><<<eblocks, 256, 0, stream>>>(
            scalars, srcp, dstp, brev, ei, nib, tabs, batch_scalars,
            acc, lossp, out, out + N_EDGES);
        finalize_nodes<NXCD><<<(N_NODES + 255) / 256, 256, 0, stream>>>(
            scalars, brev, ei, nib, tabs, batch_scalars, acc, lossp, out, out + N_EDGES);
    } else {
        edge_kernel<0><<<eblocks, 256, 0, stream>>>(
            scalars, srcp, dstp, brev, ei, nib, tabs, batch_scalars,
            acc, lossp, out, out + N_EDGES);
        finalize_nodes<1><<<(N_NODES + 255) / 256, 256, 0, stream>>>(
            scalars, brev, ei, nib, tabs, batch_scalars, acc, lossp, out, out + N_EDGES);
    }
}

// Round 4
// 170.223 us; speedup vs baseline: 1.1009x; 1.0255x over previous
//
#include <hip/hip_runtime.h>
#include <math.h>
#include <stdint.h>

#define N_NODES 100000
#define N_EDGES 1000000
#define N_NONLOOP (N_EDGES - N_NODES)          // 900000 edges needing accumulation
#define NXCD 8

// ---- binned-accumulation geometry ----
#define NP    8          // node partitions
#define PSZ   12500      // nodes per partition (100000/8)
#define PCAP  120000     // slot capacity per partition (mean 112.5K, >20 sigma margin)
#define GOWN  8          // owner blocks per partition in bin_accum
#define PROW  12544      // padded partial-row stride (floats, 64B-aligned)

// Q20 fixed-point (fallback path only)
#define ACC_SCALE   1048576.0f
#define ACC_INV     (1.0f / 1048576.0f)

typedef float  vfloat4 __attribute__((ext_vector_type(4)));
typedef int    vint4   __attribute__((ext_vector_type(4)));
typedef unsigned long long u64;

// HW_REG_XCC_ID = 20 on gfx940+; read bits [3:0]
#define XCC_ID_HWREG (20 | ((4 - 1) << 11))
__device__ __forceinline__ int get_xcc() {
    return __builtin_amdgcn_s_getreg(XCC_ID_HWREG) & (NXCD - 1);
}
__device__ __forceinline__ void l2_atomic_add_u32(uint32_t* p, uint32_t v) {
    asm volatile("global_atomic_add %0, %1, off" :: "v"(p), "v"(v) : "memory");
}
__device__ __forceinline__ void l2_atomic_add_f32(float* p, float v) {
    asm volatile("global_atomic_add_f32 %0, %1, off" :: "v"(p), "v"(v) : "memory");
}

__device__ __forceinline__ float get_invtau(const int* __restrict__ training_step) {
    int step = training_step[0];
    float tau;
    if (step == -1) {
        tau = 0.1f;  // TEMP_EVAL
    } else {
        float frac = fminf((float)step / 10000.0f, 1.0f);
        tau = 1.0f + (0.1f - 1.0f) * frac;
    }
    return 1.0f / tau;
}

__device__ __forceinline__ float wave_reduce(float v) {
    #pragma unroll
    for (int off = 32; off > 0; off >>= 1) v += __shfl_down(v, off, 64);
    return v;
}

// ---------------------------------------------------------------------------
// K1: all independent precompute (same structure as round 3).
//   blocks [0,132):   tabs, one block/entry, 4-wave K-split.
//   next 391 blocks:  nib[n], zero {lossp, loss, cnt | acc copies}.
//   next 977 blocks:  ei[e] packed edge_states (1 MB L2-class gather table).
// ncopies: 0 = binned mode (zero cnt), >=1 = fallback (zero acc copies).
// ---------------------------------------------------------------------------
#define TAB_BLOCKS  132
#define NODE_BLOCKS 391
#define EI_BLOCKS   977

__global__ __launch_bounds__(256) void fused_pre(
    const int* __restrict__ node_states,
    const int* __restrict__ edge_states,
    const float* __restrict__ node_emb,
    const float* __restrict__ edge_emb,
    const float* __restrict__ cW, const float* __restrict__ cb,
    const float* __restrict__ kW, const float* __restrict__ kb,
    const float* __restrict__ pW, const float* __restrict__ pb,
    const float* __restrict__ pnW, const float* __restrict__ pnb,
    const float* __restrict__ iW, const float* __restrict__ ib,
    const int* __restrict__ tstep,
    uint32_t* __restrict__ acc,
    uint32_t* __restrict__ cnt,
    uint8_t* __restrict__ ei,
    uint8_t* __restrict__ nib,
    float* __restrict__ tabs,
    float* __restrict__ lossp,
    float* __restrict__ loss_out,
    int ncopies)
{
    const int b = blockIdx.x;

    if (b < TAB_BLOCKS) {
        const int w    = b;                       // 0..131
        const int lane = threadIdx.x & 63;
        const int wv   = threadIdx.x >> 6;
        const float invtau = get_invtau(tstep);
        __shared__ float part[4];

        float p = 0.f;
        if (w < 128) {
            const int isB = w >> 6, h = (w >> 4) & 3, i = w & 15;
            const float* emb = isB ? node_emb : edge_emb;
            const float* cWh = cW + isB * 128 * 128;
            float t0 = 0.f, t1 = 0.f;
            const int l0 = wv * 32;
            #pragma unroll 8
            for (int l = l0; l < l0 + 32; ++l) {
                const float el = emb[i * 128 + l];          // wave-uniform
                t0 += el * cWh[l * 128 + lane];
                t1 += el * cWh[l * 128 + 64 + lane];
            }
            const float* W = (h == 0) ? kW : (h == 1) ? pW : (h == 2) ? pnW : iW;
            const float wd0 = W[2 * lane] - W[2 * lane + 1];
            const float wd1 = W[2 * (lane + 64)] - W[2 * (lane + 64) + 1];
            p = t0 * wd0 + t1 * wd1;
        } else if (wv == 0) {
            const int h = w & 3;
            const float* W = (h == 0) ? kW : (h == 1) ? pW : (h == 2) ? pnW : iW;
            const float wd0 = W[2 * lane] - W[2 * lane + 1];
            const float wd1 = W[2 * (lane + 64)] - W[2 * (lane + 64) + 1];
            p = cb[lane] * wd0 + cb[64 + lane] * wd1;
        }
        p = wave_reduce(p);
        if (lane == 0) part[wv] = p;
        __syncthreads();
        if (threadIdx.x == 0) {
            const float tot = part[0] + part[1] + part[2] + part[3];
            if (w < 128) {
                const int isB = w >> 6, h = (w >> 4) & 3, i = w & 15;
                tabs[isB * 64 + i * 4 + h] = tot * invtau;
            } else {
                const int h = w & 3;
                const float* bb = (h == 0) ? kb : (h == 1) ? pb : (h == 2) ? pnb : ib;
                tabs[128 + h] = (tot + bb[0] - bb[1]) * invtau;
            }
        }
        return;
    }

    if (b < TAB_BLOCKS + NODE_BLOCKS) {
        const int n = (b - TAB_BLOCKS) * 256 + threadIdx.x;
        if (n < 256) lossp[n] = 0.f;
        if (n == 0) *loss_out = 0.f;
        if (ncopies == 0) {
            if (n < NP) cnt[n] = 0u;
        }
        if (n < N_NODES) {
            vint4 st = __builtin_nontemporal_load(&((const vint4*)node_states)[n]);
            nib[n] = (uint8_t)(st.x + 2 * st.y + 4 * st.z + 8 * st.w);
            for (int k = 0; k < ncopies; ++k) acc[(size_t)k * N_NODES + n] = 0u;
        }
        return;
    }

    // ---- ei packing: 4 edges/thread, streaming NT reads, uint32 write ----
    const int t = (b - TAB_BLOCKS - NODE_BLOCKS) * 256 + threadIdx.x;
    if (t < N_EDGES / 4) {
        const vint4* esp = (const vint4*)edge_states + 4 * t;
        vint4 e0 = __builtin_nontemporal_load(esp + 0);
        vint4 e1 = __builtin_nontemporal_load(esp + 1);
        vint4 e2 = __builtin_nontemporal_load(esp + 2);
        vint4 e3 = __builtin_nontemporal_load(esp + 3);
        const uint32_t i0 = e0.x + 2 * e0.y + 4 * e0.z + 8 * e0.w;
        const uint32_t i1 = e1.x + 2 * e1.y + 4 * e1.z + 8 * e1.w;
        const uint32_t i2 = e2.x + 2 * e2.y + 4 * e2.z + 8 * e2.w;
        const uint32_t i3 = e3.x + 2 * e3.y + 4 * e3.z + 8 * e3.w;
        ((uint32_t*)ei)[t] = i0 | (i1 << 8) | (i2 << 16) | (i3 << 24);
    }
}

// ---------------------------------------------------------------------------
// K2a (binned): per-edge compute + partition-compaction. NO per-edge device
// atomics. Device atomics: 8 reserve-adds per block (7K total) + 1 loss
// add per wave (3.5K total).
// ---------------------------------------------------------------------------
__global__ __launch_bounds__(256) void edge_compact(
    const float* __restrict__ s,
    const int* __restrict__ src,
    const int* __restrict__ dst,
    const int* __restrict__ brev,
    const uint8_t* __restrict__ ei,
    const uint8_t* __restrict__ nib,
    const float* __restrict__ tabs,
    const float* __restrict__ target,
    uint32_t* __restrict__ cnt,
    u64* __restrict__ pairs,
    float* __restrict__ lossp,
    float* __restrict__ out)
{
    __shared__ float4 sf[33];
    __shared__ uint32_t hist[NP], lbase[NP], loff[NP];
    const int tid = threadIdx.x;
    if (tid < 33) sf[tid] = ((const float4*)tabs)[tid];
    if (tid < NP) { hist[tid] = 0u; loff[tid] = 0u; }
    __syncthreads();

    const int t = blockIdx.x * 256 + tid;          // 0 .. 225023
    const bool active = (t < N_NONLOOP / 4);
    float lsum = 0.f;
    float ov[4], av[4];
    int   pj[4], dloc[4];
    int   g = 0;

    if (active) {
        g = (N_NODES / 4) + t;  // 16B-aligned quad index
        const vint4   rv = __builtin_nontemporal_load(&((const vint4*)brev)[g]);
        const vint4   sr = __builtin_nontemporal_load(&((const vint4*)src)[g]);
        const vint4   ds = __builtin_nontemporal_load(&((const vint4*)dst)[g]);
        const vfloat4 sv = __builtin_nontemporal_load(&((const vfloat4*)s)[g]);
        const vfloat4 tg = __builtin_nontemporal_load(&((const vfloat4*)target)[g]);

        const int rvv[4] = {rv.x, rv.y, rv.z, rv.w};
        const int srv[4] = {sr.x, sr.y, sr.z, sr.w};
        const int dsv[4] = {ds.x, ds.y, ds.z, ds.w};
        const float svv[4] = {sv.x, sv.y, sv.z, sv.w};
        const float tgv[4] = {tg.x, tg.y, tg.z, tg.w};

        int   eidx[4], ni[4];
        float ss[4], sd[4];
        #pragma unroll
        for (int j = 0; j < 4; ++j) {
            eidx[j] = ei[rvv[j]];
            ni[j]   = nib[srv[j]];
            ss[j]   = s[srv[j]];
            sd[j]   = s[dsv[j]];
        }

        const float4 c4 = sf[32];
        #pragma unroll
        for (int j = 0; j < 4; ++j) {
            const float4 a = sf[eidx[j]];
            const float4 b = sf[16 + ni[j]];
            const float lk  = a.x + b.x + c4.x;
            const float lp  = a.y + b.y + c4.y;
            const float lpn = a.z + b.z + c4.z;
            const float li  = a.w + b.w + c4.w;
            const float pk  = 1.f / (1.f + __expf(-lk));
            const float pp  = 1.f / (1.f + __expf(-lp));
            const float ppn = 1.f / (1.f + __expf(-lpn));
            const float pi  = 1.f / (1.f + __expf(-li));

            const float s_wo = svv[j] - sd[j];
            const float s_w  = s_wo + ss[j];
            av[j] = pp * s_wo + ppn * s_w;

            const uint32_t p = (uint32_t)dsv[j] / 12500u;
            pj[j]   = (int)p;
            dloc[j] = dsv[j] - (int)p * 12500;

            ov[j] = pi + svv[j] * pk;
            const float d = tgv[j] - ov[j];
            lsum += d * d;
        }
        #pragma unroll
        for (int j = 0; j < 4; ++j) atomicAdd(&hist[pj[j]], 1u);
    }

    __syncthreads();
    if (tid < NP) lbase[tid] = atomicAdd(&cnt[tid], hist[tid]);   // global reserve
    __syncthreads();

    if (active) {
        #pragma unroll
        for (int j = 0; j < 4; ++j) {
            const uint32_t k    = atomicAdd(&loff[pj[j]], 1u);    // LDS ticket
            const uint32_t slot = lbase[pj[j]] + k;
            if (slot < PCAP)
                pairs[(size_t)pj[j] * PCAP + slot] =
                    ((u64)(uint32_t)dloc[j] << 32) | (uint32_t)__float_as_int(av[j]);
        }
        vfloat4 o4 = {ov[0], ov[1], ov[2], ov[3]};
        __builtin_nontemporal_store(o4, &((vfloat4*)out)[g]);
    }

    lsum = wave_reduce(lsum);
    if ((tid & 63) == 0)
        atomicAdd(&lossp[(blockIdx.x & 15) * 16], lsum);          // 16 spread cells
}

// ---------------------------------------------------------------------------
// K2b (binned): 8 partitions x 8 owner blocks. Each block LDS-accumulates its
// chunk of the partition's pair stream, flushes one coalesced partial row.
// LDS atomics only -- zero coherence-point traffic.
// ---------------------------------------------------------------------------
__global__ __launch_bounds__(256) void bin_accum(
    const u64* __restrict__ pairs,
    const uint32_t* __restrict__ cnt,
    float* __restrict__ partials)
{
    __shared__ float part[PSZ];
    const int tid = threadIdx.x;
    const int p = blockIdx.x >> 3, r = blockIdx.x & 7;

    for (int k = tid; k < PSZ; k += 256) part[k] = 0.f;
    __syncthreads();

    uint32_t c = cnt[p];
    if (c > PCAP) c = PCAP;
    const uint32_t chunk = (c + GOWN - 1) / GOWN;
    const uint32_t lo = r * chunk;
    uint32_t hi = lo + chunk;
    if (hi > c) hi = c;

    const u64* pp = pairs + (size_t)p * PCAP;
    for (uint32_t i = lo + tid; i < hi; i += 256) {
        const u64 v = pp[i];
        atomicAdd(&part[(uint32_t)(v >> 32)], __int_as_float((int)(uint32_t)v));
    }
    __syncthreads();

    float* row = partials + (size_t)blockIdx.x * PROW;
    for (int k = tid; k < PSZ; k += 256) row[k] = part[k];
}

// ---------------------------------------------------------------------------
// K3 (binned): out[n] = pi + s[n]*(pk+ppn) + sum_r partials[(p*8+r)][off].
// Block 0 folds the 16 edge-loss cells.
// ---------------------------------------------------------------------------
__global__ __launch_bounds__(256) void finalize_binned(
    const float* __restrict__ s,
    const int* __restrict__ brev,
    const uint8_t* __restrict__ ei,
    const uint8_t* __restrict__ nib,
    const float* __restrict__ tabs,
    const float* __restrict__ target,
    const float* __restrict__ partials,
    const float* __restrict__ lossp,
    float* __restrict__ out,
    float* __restrict__ loss_out)
{
    __shared__ float4 sf[33];
    if (threadIdx.x < 33) sf[threadIdx.x] = ((const float4*)tabs)[threadIdx.x];
    __syncthreads();

    const int n = blockIdx.x * blockDim.x + threadIdx.x;
    const bool active = (n < N_NODES);
    float sq = 0.f, v = 0.f;
    if (active) {
        const int  eidx = ei[brev[n]];
        const int  ni   = nib[n];
        const float sv  = s[n];

        const uint32_t p   = (uint32_t)n / 12500u;
        const uint32_t off = (uint32_t)n - p * 12500u;
        const float* pr = partials + (size_t)p * GOWN * PROW + off;
        float a8 = 0.f;
        #pragma unroll
        for (int r = 0; r < GOWN; ++r) a8 += pr[(size_t)r * PROW];

        const float4 a  = sf[eidx];
        const float4 b  = sf[16 + ni];
        const float4 c4 = sf[32];
        const float lk  = a.x + b.x + c4.x;
        const float lpn = a.z + b.z + c4.z;
        const float li  = a.w + b.w + c4.w;
        const float pk  = 1.f / (1.f + __expf(-lk));
        const float ppn = 1.f / (1.f + __expf(-lpn));
        const float pi  = 1.f / (1.f + __expf(-li));

        v = pi + sv * (pk + ppn) + a8;
        const float d = target[n] - v;
        sq = d * d;
    }
    sq = wave_reduce(sq);
    __shared__ float wsum[4];
    const int lane = threadIdx.x & 63, wid = threadIdx.x >> 6;
    if (lane == 0) wsum[wid] = sq;
    __syncthreads();
    if (threadIdx.x == 0) {
        float tot = (wsum[0] + wsum[1] + wsum[2] + wsum[3]) * (1.0f / (float)N_EDGES);
        if (blockIdx.x == 0) {
            #pragma unroll
            for (int c = 0; c < 16; ++c) tot += lossp[c * 16] * (1.0f / (float)N_EDGES);
        }
        atomicAdd(loss_out, tot);
    }
    if (active) out[n] = v;
}

// ---------------------------------------------------------------------------
// Fallback path (round-3 verified): per-XCD u32 Q20 atomics / device-scope.
// ---------------------------------------------------------------------------
template<int MODE>
__global__ __launch_bounds__(256) void edge_kernel(
    const float* __restrict__ s,
    const int* __restrict__ src,
    const int* __restrict__ dst,
    const int* __restrict__ brev,
    const uint8_t* __restrict__ ei,
    const uint8_t* __restrict__ nib,
    const float* __restrict__ tabs,
    const float* __restrict__ target,
    uint32_t* __restrict__ acc,
    float* __restrict__ lossp,
    float* __restrict__ out,
    float* __restrict__ loss_out)
{
    __shared__ float4 sf[MODE ? 160 : 33];
    if (threadIdx.x < 33) sf[threadIdx.x] = ((const float4*)tabs)[threadIdx.x];
    __syncthreads();

    int xcc = 0;
    uint32_t* accx = acc;
    if (MODE == 1) {
        xcc  = get_xcc();
        accx = acc + (size_t)xcc * N_NODES;
    }

    const int t = blockIdx.x * blockDim.x + threadIdx.x;
    const bool active = (t < N_NONLOOP / 4);
    float lsum = 0.f;
    float ov[4];
    int   iv[4];
    int   dsv[4];
    int   g = 0;

    if (active) {
        g = (N_NODES / 4) + t;
        const vint4   rv = __builtin_nontemporal_load(&((const vint4*)brev)[g]);
        const vint4   sr = __builtin_nontemporal_load(&((const vint4*)src)[g]);
        const vint4   ds = __builtin_nontemporal_load(&((const vint4*)dst)[g]);
        const vfloat4 sv = __builtin_nontemporal_load(&((const vfloat4*)s)[g]);
        const vfloat4 tg = __builtin_nontemporal_load(&((const vfloat4*)target)[g]);

        const int rvv[4] = {rv.x, rv.y, rv.z, rv.w};
        const int srv[4] = {sr.x, sr.y, sr.z, sr.w};
        dsv[0] = ds.x; dsv[1] = ds.y; dsv[2] = ds.z; dsv[3] = ds.w;
        const float svv[4] = {sv.x, sv.y, sv.z, sv.w};
        const float tgv[4] = {tg.x, tg.y, tg.z, tg.w};

        int   eidx[4], ni[4];
        float ss[4], sd[4];
        #pragma unroll
        for (int j = 0; j < 4; ++j) {
            eidx[j] = ei[rvv[j]];
            ni[j]   = nib[srv[j]];
            ss[j]   = s[srv[j]];
            sd[j]   = s[dsv[j]];
        }

        const float4 c4 = sf[32];
        #pragma unroll
        for (int j = 0; j < 4; ++j) {
            const float4 a = sf[eidx[j]];
            const float4 b = sf[16 + ni[j]];
            const float lk  = a.x + b.x + c4.x;
            const float lp  = a.y + b.y + c4.y;
            const float lpn = a.z + b.z + c4.z;
            const float li  = a.w + b.w + c4.w;
            const float pk  = 1.f / (1.f + __expf(-lk));
            const float pp  = 1.f / (1.f + __expf(-lp));
            const float ppn = 1.f / (1.f + __expf(-lpn));
            const float pi  = 1.f / (1.f + __expf(-li));

            const float s_wo = svv[j] - sd[j];
            const float s_w  = s_wo + ss[j];
            iv[j] = __float2int_rn((pp * s_wo + ppn * s_w) * ACC_SCALE);

            ov[j] = pi + svv[j] * pk;
            const float d = tgv[j] - ov[j];
            lsum += d * d;
        }
    }

    lsum = wave_reduce(lsum);
    __shared__ float wsum[4];
    const int lane = threadIdx.x & 63, wid = threadIdx.x >> 6;
    if (lane == 0) wsum[wid] = lsum;
    __syncthreads();
    if (threadIdx.x == 0) {
        const float tot = (wsum[0] + wsum[1] + wsum[2] + wsum[3]) * (1.0f / (float)N_EDGES);
        if (MODE == 1) l2_atomic_add_f32(&lossp[xcc * 32], tot);
        else           atomicAdd(loss_out, tot);
    }

    if (active) {
        #pragma unroll
        for (int j = 0; j < 4; ++j) {
            if (MODE == 1) l2_atomic_add_u32(&accx[dsv[j]], (uint32_t)iv[j]);
            else           atomicAdd((unsigned int*)&acc[dsv[j]], (unsigned int)iv[j]);
        }
        vfloat4 o4 = {ov[0], ov[1], ov[2], ov[3]};
        __builtin_nontemporal_store(o4, &((vfloat4*)out)[g]);
    }
}

template<int NC>
__global__ __launch_bounds__(256) void finalize_nodes(
    const float* __restrict__ s,
    const int* __restrict__ brev,
    const uint8_t* __restrict__ ei,
    const uint8_t* __restrict__ nib,
    const float* __restrict__ tabs,
    const float* __restrict__ target,
    const uint32_t* __restrict__ acc,
    const float* __restrict__ lossp,
    float* __restrict__ out,
    float* __restrict__ loss_out)
{
    __shared__ float4 sf[33];
    if (threadIdx.x < 33) sf[threadIdx.x] = ((const float4*)tabs)[threadIdx.x];
    __syncthreads();

    const int n = blockIdx.x * blockDim.x + threadIdx.x;
    const bool active = (n < N_NODES);
    float sq = 0.f, v = 0.f;
    if (active) {
        const int  eidx = ei[brev[n]];
        const int  ni   = nib[n];
        const float sv  = s[n];

        uint32_t asum = 0u;
        #pragma unroll
        for (int k = 0; k < NC; ++k) asum += acc[(size_t)k * N_NODES + n];
        const float a8 = (float)(int)asum * ACC_INV;

        const float4 a  = sf[eidx];
        const float4 b  = sf[16 + ni];
        const float4 c4 = sf[32];
        const float lk  = a.x + b.x + c4.x;
        const float lpn = a.z + b.z + c4.z;
        const float li  = a.w + b.w + c4.w;
        const float pk  = 1.f / (1.f + __expf(-lk));
        const float ppn = 1.f / (1.f + __expf(-lpn));
        const float pi  = 1.f / (1.f + __expf(-li));

        v = pi + sv * (pk + ppn) + a8;
        const float d = target[n] - v;
        sq = d * d;
    }
    sq = wave_reduce(sq);
    __shared__ float wsum[4];
    const int lane = threadIdx.x & 63, wid = threadIdx.x >> 6;
    if (lane == 0) wsum[wid] = sq;
    __syncthreads();
    if (threadIdx.x == 0) {
        float tot = (wsum[0] + wsum[1] + wsum[2] + wsum[3]) * (1.0f / (float)N_EDGES);
        if (blockIdx.x == 0) {
            #pragma unroll
            for (int k = 0; k < NXCD; ++k) tot += lossp[k * 32];
        }
        atomicAdd(loss_out, tot);
    }
    if (active) out[n] = v;
}

extern "C" void kernel_launch(void* const* d_in, const int* in_sizes, int n_in,
                              void* d_out, int out_size, void* d_ws, size_t ws_size,
                              hipStream_t stream) {
    const int*   node_states   = (const int*)d_in[0];
    const int*   edge_states   = (const int*)d_in[1];
    const float* scalars       = (const float*)d_in[2];
    const int*   edge_index    = (const int*)d_in[3];
    const int*   brev          = (const int*)d_in[4];
    const float* batch_scalars = (const float*)d_in[5];
    // d_in[6] = processor_step (batch axis-1 size 1 -> index 0)
    const int*   training_step = (const int*)d_in[7];
    const float* node_emb  = (const float*)d_in[8];
    const float* edge_emb  = (const float*)d_in[9];
    const float* combine_W = (const float*)d_in[10];
    const float* combine_b = (const float*)d_in[11];
    const float* keep_W  = (const float*)d_in[12];
    const float* keep_b  = (const float*)d_in[13];
    const float* push_W  = (const float*)d_in[14];
    const float* push_b  = (const float*)d_in[15];
    const float* pushn_W = (const float*)d_in[16];
    const float* pushn_b = (const float*)d_in[17];
    const float* inc_W   = (const float*)d_in[18];
    const float* inc_b   = (const float*)d_in[19];

    float* out = (float*)d_out;  // [0..E) new_scalars, [E] loss

    const int* srcp = edge_index;
    const int* dstp = edge_index + N_EDGES;

    // ---- workspace budgets ----
    const size_t PAIRS_B    = (size_t)NP * PCAP * 8;        // 7,680,000
    const size_t PARTIALS_B = (size_t)NP * GOWN * PROW * 4; // 3,211,264
    const size_t need_binned = 3072 + PAIRS_B + PARTIALS_B + N_EDGES + N_NODES; // ~11.99 MB
    const size_t need_scoped = 2048 + (size_t)NXCD * N_NODES * 4 + N_EDGES + N_NODES; // ~4.3 MB

    char* ws = (char*)d_ws;
    const int ethreads = N_NONLOOP / 4;   // 225000
    const int eblocks  = (ethreads + 255) / 256;

    if (ws_size >= need_binned) {
        // ---- binned (atomic-free accumulation) path ----
        float*    tabs     = (float*)ws;                         // 1 KiB
        float*    lossp    = (float*)(ws + 1024);                // 1 KiB (16 cells x 64B)
        uint32_t* cnt      = (uint32_t*)(ws + 2048);             // 1 KiB pad
        u64*      pairs    = (u64*)(ws + 3072);                  // 7.68 MB
        float*    partials = (float*)(ws + 3072 + PAIRS_B);      // 3.21 MB
        uint8_t*  ei       = (uint8_t*)(ws + 3072 + PAIRS_B + PARTIALS_B);
        uint8_t*  nib      = ei + N_EDGES;

        fused_pre<<<TAB_BLOCKS + NODE_BLOCKS + EI_BLOCKS, 256, 0, stream>>>(
            node_states, edge_states, node_emb, edge_emb,
            combine_W, combine_b, keep_W, keep_b, push_W, push_b,
            pushn_W, pushn_b, inc_W, inc_b, training_step,
            nullptr, cnt, ei, nib, tabs, lossp, out + N_EDGES, 0);

        edge_compact<<<eblocks, 256, 0, stream>>>(
            scalars, srcp, dstp, brev, ei, nib, tabs, batch_scalars,
            cnt, pairs, lossp, out);

        bin_accum<<<NP * GOWN, 256, 0, stream>>>(pairs, cnt, partials);

        finalize_binned<<<(N_NODES + 255) / 256, 256, 0, stream>>>(
            scalars, brev, ei, nib, tabs, batch_scalars, partials, lossp,
            out, out + N_EDGES);
    } else {
        const bool scoped = (ws_size >= need_scoped);
        const int nc = scoped ? NXCD : 1;

        float*    tabs  = (float*)ws;
        float*    lossp = (float*)(ws + 1024);
        uint32_t* acc   = (uint32_t*)(ws + 2048);
        uint8_t*  ei    = (uint8_t*)(ws + 2048 + (size_t)nc * N_NODES * 4);
        uint8_t*  nib   = ei + N_EDGES;

        fused_pre<<<TAB_BLOCKS + NODE_BLOCKS + EI_BLOCKS, 256, 0, stream>>>(
            node_states, edge_states, node_emb, edge_emb,
            combine_W, combine_b, keep_W, keep_b, push_W, push_b,
            pushn_W, pushn_b, inc_W, inc_b, training_step,
            acc, nullptr, ei, nib, tabs, lossp, out + N_EDGES, nc);

        if (scoped) {
            edge_kernel<1><<<eblocks, 256, 0, stream>>>(
                scalars, srcp, dstp, brev, ei, nib, tabs, batch_scalars,
                acc, lossp, out, out + N_EDGES);
            finalize_nodes<NXCD><<<(N_NODES + 255) / 256, 256, 0, stream>>>(
                scalars, brev, ei, nib, tabs, batch_scalars, acc, lossp,
                out, out + N_EDGES);
        } else {
            edge_kernel<0><<<eblocks, 256, 0, stream>>>(
                scalars, srcp, dstp, brev, ei, nib, tabs, batch_scalars,
                acc, lossp, out, out + N_EDGES);
            finalize_nodes<1><<<(N_NODES + 255) / 256, 256, 0, stream>>>(
                scalars, brev, ei, nib, tabs, batch_scalars, acc, lossp,
                out, out + N_EDGES);
        }
    }
}

// Round 5
// 156.501 us; speedup vs baseline: 1.1974x; 1.0877x over previous
//
#include <hip/hip_runtime.h>
#include <math.h>
#include <stdint.h>

#define N_NODES 100000
#define N_EDGES 1000000
#define N_NONLOOP (N_EDGES - N_NODES)          // 900000 edges needing accumulation
#define NXCD 8

// ---- binned-accumulation geometry (round 5: 4x accumulate parallelism) ----
#define NP    16         // node partitions
#define PSZ   6250       // nodes per partition (100000/16)
#define PCAP  61440      // slot capacity per partition (mean 56.25K, +22 sigma)
#define GOWN  16         // owner blocks per partition in bin_accum -> 256 blocks
#define PROW  6272       // padded partial-row stride (floats, 64B-aligned)

// Q20 fixed-point (fallback path only)
#define ACC_SCALE   1048576.0f
#define ACC_INV     (1.0f / 1048576.0f)

typedef float  vfloat4 __attribute__((ext_vector_type(4)));
typedef int    vint4   __attribute__((ext_vector_type(4)));
typedef unsigned long long u64;

// HW_REG_XCC_ID = 20 on gfx940+; read bits [3:0]
#define XCC_ID_HWREG (20 | ((4 - 1) << 11))
__device__ __forceinline__ int get_xcc() {
    return __builtin_amdgcn_s_getreg(XCC_ID_HWREG) & (NXCD - 1);
}
__device__ __forceinline__ void l2_atomic_add_u32(uint32_t* p, uint32_t v) {
    asm volatile("global_atomic_add %0, %1, off" :: "v"(p), "v"(v) : "memory");
}
__device__ __forceinline__ void l2_atomic_add_f32(float* p, float v) {
    asm volatile("global_atomic_add_f32 %0, %1, off" :: "v"(p), "v"(v) : "memory");
}

__device__ __forceinline__ float get_invtau(const int* __restrict__ training_step) {
    int step = training_step[0];
    float tau;
    if (step == -1) {
        tau = 0.1f;  // TEMP_EVAL
    } else {
        float frac = fminf((float)step / 10000.0f, 1.0f);
        tau = 1.0f + (0.1f - 1.0f) * frac;
    }
    return 1.0f / tau;
}

__device__ __forceinline__ float wave_reduce(float v) {
    #pragma unroll
    for (int off = 32; off > 0; off >>= 1) v += __shfl_down(v, off, 64);
    return v;
}

// ---------------------------------------------------------------------------
// K1: all independent precompute.
//   blocks [0,132):   tabs, one block/entry, 4-wave K-split.
//   next 391 blocks:  nib[n], zero {lossp, loss, cnt | acc copies}.
//   next 977 blocks:  ei[e] packed edge_states (1 MB L2-class gather table).
// ncopies: 0 = binned mode (zero cnt), >=1 = fallback (zero acc copies).
// ---------------------------------------------------------------------------
#define TAB_BLOCKS  132
#define NODE_BLOCKS 391
#define EI_BLOCKS   977

__global__ __launch_bounds__(256) void fused_pre(
    const int* __restrict__ node_states,
    const int* __restrict__ edge_states,
    const float* __restrict__ node_emb,
    const float* __restrict__ edge_emb,
    const float* __restrict__ cW, const float* __restrict__ cb,
    const float* __restrict__ kW, const float* __restrict__ kb,
    const float* __restrict__ pW, const float* __restrict__ pb,
    const float* __restrict__ pnW, const float* __restrict__ pnb,
    const float* __restrict__ iW, const float* __restrict__ ib,
    const int* __restrict__ tstep,
    uint32_t* __restrict__ acc,
    uint32_t* __restrict__ cnt,
    uint8_t* __restrict__ ei,
    uint8_t* __restrict__ nib,
    float* __restrict__ tabs,
    float* __restrict__ lossp,
    float* __restrict__ loss_out,
    int ncopies)
{
    const int b = blockIdx.x;

    if (b < TAB_BLOCKS) {
        const int w    = b;                       // 0..131
        const int lane = threadIdx.x & 63;
        const int wv   = threadIdx.x >> 6;
        const float invtau = get_invtau(tstep);
        __shared__ float part[4];

        float p = 0.f;
        if (w < 128) {
            const int isB = w >> 6, h = (w >> 4) & 3, i = w & 15;
            const float* emb = isB ? node_emb : edge_emb;
            const float* cWh = cW + isB * 128 * 128;
            float t0 = 0.f, t1 = 0.f;
            const int l0 = wv * 32;
            #pragma unroll 8
            for (int l = l0; l < l0 + 32; ++l) {
                const float el = emb[i * 128 + l];          // wave-uniform
                t0 += el * cWh[l * 128 + lane];
                t1 += el * cWh[l * 128 + 64 + lane];
            }
            const float* W = (h == 0) ? kW : (h == 1) ? pW : (h == 2) ? pnW : iW;
            const float wd0 = W[2 * lane] - W[2 * lane + 1];
            const float wd1 = W[2 * (lane + 64)] - W[2 * (lane + 64) + 1];
            p = t0 * wd0 + t1 * wd1;
        } else if (wv == 0) {
            const int h = w & 3;
            const float* W = (h == 0) ? kW : (h == 1) ? pW : (h == 2) ? pnW : iW;
            const float wd0 = W[2 * lane] - W[2 * lane + 1];
            const float wd1 = W[2 * (lane + 64)] - W[2 * (lane + 64) + 1];
            p = cb[lane] * wd0 + cb[64 + lane] * wd1;
        }
        p = wave_reduce(p);
        if (lane == 0) part[wv] = p;
        __syncthreads();
        if (threadIdx.x == 0) {
            const float tot = part[0] + part[1] + part[2] + part[3];
            if (w < 128) {
                const int isB = w >> 6, h = (w >> 4) & 3, i = w & 15;
                tabs[isB * 64 + i * 4 + h] = tot * invtau;
            } else {
                const int h = w & 3;
                const float* bb = (h == 0) ? kb : (h == 1) ? pb : (h == 2) ? pnb : ib;
                tabs[128 + h] = (tot + bb[0] - bb[1]) * invtau;
            }
        }
        return;
    }

    if (b < TAB_BLOCKS + NODE_BLOCKS) {
        const int n = (b - TAB_BLOCKS) * 256 + threadIdx.x;
        if (n < 256) lossp[n] = 0.f;
        if (n == 0) *loss_out = 0.f;
        if (ncopies == 0) {
            if (n < NP) cnt[n] = 0u;
        }
        if (n < N_NODES) {
            vint4 st = __builtin_nontemporal_load(&((const vint4*)node_states)[n]);
            nib[n] = (uint8_t)(st.x + 2 * st.y + 4 * st.z + 8 * st.w);
            for (int k = 0; k < ncopies; ++k) acc[(size_t)k * N_NODES + n] = 0u;
        }
        return;
    }

    // ---- ei packing: 4 edges/thread, streaming NT reads, uint32 write ----
    const int t = (b - TAB_BLOCKS - NODE_BLOCKS) * 256 + threadIdx.x;
    if (t < N_EDGES / 4) {
        const vint4* esp = (const vint4*)edge_states + 4 * t;
        vint4 e0 = __builtin_nontemporal_load(esp + 0);
        vint4 e1 = __builtin_nontemporal_load(esp + 1);
        vint4 e2 = __builtin_nontemporal_load(esp + 2);
        vint4 e3 = __builtin_nontemporal_load(esp + 3);
        const uint32_t i0 = e0.x + 2 * e0.y + 4 * e0.z + 8 * e0.w;
        const uint32_t i1 = e1.x + 2 * e1.y + 4 * e1.z + 8 * e1.w;
        const uint32_t i2 = e2.x + 2 * e2.y + 4 * e2.z + 8 * e2.w;
        const uint32_t i3 = e3.x + 2 * e3.y + 4 * e3.z + 8 * e3.w;
        ((uint32_t*)ei)[t] = i0 | (i1 << 8) | (i2 << 16) | (i3 << 24);
    }
}

// ---------------------------------------------------------------------------
// K2a (binned): per-edge compute + partition-compaction. NO per-edge device
// atomics. Device atomics: NP reserve-adds per block (~14K total) + 1 loss
// add per wave (3.5K total).
// ---------------------------------------------------------------------------
__global__ __launch_bounds__(256) void edge_compact(
    const float* __restrict__ s,
    const int* __restrict__ src,
    const int* __restrict__ dst,
    const int* __restrict__ brev,
    const uint8_t* __restrict__ ei,
    const uint8_t* __restrict__ nib,
    const float* __restrict__ tabs,
    const float* __restrict__ target,
    uint32_t* __restrict__ cnt,
    u64* __restrict__ pairs,
    float* __restrict__ lossp,
    float* __restrict__ out)
{
    __shared__ float4 sf[33];
    __shared__ uint32_t hist[NP], lbase[NP], loff[NP];
    const int tid = threadIdx.x;
    if (tid < 33) sf[tid] = ((const float4*)tabs)[tid];
    if (tid < NP) { hist[tid] = 0u; loff[tid] = 0u; }
    __syncthreads();

    const int t = blockIdx.x * 256 + tid;          // 0 .. 225023
    const bool active = (t < N_NONLOOP / 4);
    float lsum = 0.f;
    float ov[4], av[4];
    int   pj[4], dloc[4];
    int   g = 0;

    if (active) {
        g = (N_NODES / 4) + t;  // 16B-aligned quad index
        const vint4   rv = __builtin_nontemporal_load(&((const vint4*)brev)[g]);
        const vint4   sr = __builtin_nontemporal_load(&((const vint4*)src)[g]);
        const vint4   ds = __builtin_nontemporal_load(&((const vint4*)dst)[g]);
        const vfloat4 sv = __builtin_nontemporal_load(&((const vfloat4*)s)[g]);
        const vfloat4 tg = __builtin_nontemporal_load(&((const vfloat4*)target)[g]);

        const int rvv[4] = {rv.x, rv.y, rv.z, rv.w};
        const int srv[4] = {sr.x, sr.y, sr.z, sr.w};
        const int dsv[4] = {ds.x, ds.y, ds.z, ds.w};
        const float svv[4] = {sv.x, sv.y, sv.z, sv.w};
        const float tgv[4] = {tg.x, tg.y, tg.z, tg.w};

        int   eidx[4], ni[4];
        float ss[4], sd[4];
        #pragma unroll
        for (int j = 0; j < 4; ++j) {
            eidx[j] = ei[rvv[j]];
            ni[j]   = nib[srv[j]];
            ss[j]   = s[srv[j]];
            sd[j]   = s[dsv[j]];
        }

        const float4 c4 = sf[32];
        #pragma unroll
        for (int j = 0; j < 4; ++j) {
            const float4 a = sf[eidx[j]];
            const float4 b = sf[16 + ni[j]];
            const float lk  = a.x + b.x + c4.x;
            const float lp  = a.y + b.y + c4.y;
            const float lpn = a.z + b.z + c4.z;
            const float li  = a.w + b.w + c4.w;
            const float pk  = 1.f / (1.f + __expf(-lk));
            const float pp  = 1.f / (1.f + __expf(-lp));
            const float ppn = 1.f / (1.f + __expf(-lpn));
            const float pi  = 1.f / (1.f + __expf(-li));

            const float s_wo = svv[j] - sd[j];
            const float s_w  = s_wo + ss[j];
            av[j] = pp * s_wo + ppn * s_w;

            const uint32_t p = (uint32_t)dsv[j] / (uint32_t)PSZ;
            pj[j]   = (int)p;
            dloc[j] = dsv[j] - (int)p * PSZ;

            ov[j] = pi + svv[j] * pk;
            const float d = tgv[j] - ov[j];
            lsum += d * d;
        }
        #pragma unroll
        for (int j = 0; j < 4; ++j) atomicAdd(&hist[pj[j]], 1u);
    }

    __syncthreads();
    if (tid < NP) lbase[tid] = atomicAdd(&cnt[tid], hist[tid]);   // global reserve
    __syncthreads();

    if (active) {
        #pragma unroll
        for (int j = 0; j < 4; ++j) {
            const uint32_t k    = atomicAdd(&loff[pj[j]], 1u);    // LDS ticket
            const uint32_t slot = lbase[pj[j]] + k;
            if (slot < PCAP)
                pairs[(size_t)pj[j] * PCAP + slot] =
                    ((u64)(uint32_t)dloc[j] << 32) | (uint32_t)__float_as_int(av[j]);
        }
        vfloat4 o4 = {ov[0], ov[1], ov[2], ov[3]};
        __builtin_nontemporal_store(o4, &((vfloat4*)out)[g]);
    }

    lsum = wave_reduce(lsum);
    if ((tid & 63) == 0)
        atomicAdd(&lossp[(blockIdx.x & 15) * 16], lsum);          // 16 spread cells
}

// ---------------------------------------------------------------------------
// K2b (binned): 16 partitions x 16 owner blocks = 256 blocks (1/CU). Each
// block LDS-accumulates its ~3.5K-pair chunk into a 25KB LDS array, flushes
// one coalesced partial row. LDS atomics only -- zero coherence traffic.
// ---------------------------------------------------------------------------
__global__ __launch_bounds__(256) void bin_accum(
    const u64* __restrict__ pairs,
    const uint32_t* __restrict__ cnt,
    float* __restrict__ partials)
{
    __shared__ float part[PROW];
    const int tid = threadIdx.x;
    const int p = blockIdx.x >> 4, r = blockIdx.x & 15;

    for (int k = tid; k < PROW; k += 256) part[k] = 0.f;
    __syncthreads();

    uint32_t c = cnt[p];
    if (c > PCAP) c = PCAP;
    const uint32_t chunk = (c + GOWN - 1) / GOWN;
    const uint32_t lo = r * chunk;
    uint32_t hi = lo + chunk;
    if (hi > c) hi = c;

    const u64* pp = pairs + (size_t)p * PCAP;
    for (uint32_t i = lo + tid; i < hi; i += 256) {
        const u64 v = pp[i];
        atomicAdd(&part[(uint32_t)(v >> 32)], __int_as_float((int)(uint32_t)v));
    }
    __syncthreads();

    float* row = partials + (size_t)blockIdx.x * PROW;
    for (int k = tid; k < PSZ; k += 256) row[k] = part[k];
}

// ---------------------------------------------------------------------------
// K3 (binned): out[n] = pi + s[n]*(pk+ppn) + sum_r partials[(p*16+r)][off].
// Block 0 folds the 16 edge-loss cells.
// ---------------------------------------------------------------------------
__global__ __launch_bounds__(256) void finalize_binned(
    const float* __restrict__ s,
    const int* __restrict__ brev,
    const uint8_t* __restrict__ ei,
    const uint8_t* __restrict__ nib,
    const float* __restrict__ tabs,
    const float* __restrict__ target,
    const float* __restrict__ partials,
    const float* __restrict__ lossp,
    float* __restrict__ out,
    float* __restrict__ loss_out)
{
    __shared__ float4 sf[33];
    if (threadIdx.x < 33) sf[threadIdx.x] = ((const float4*)tabs)[threadIdx.x];
    __syncthreads();

    const int n = blockIdx.x * blockDim.x + threadIdx.x;
    const bool active = (n < N_NODES);
    float sq = 0.f, v = 0.f;
    if (active) {
        const int  eidx = ei[brev[n]];
        const int  ni   = nib[n];
        const float sv  = s[n];

        const uint32_t p   = (uint32_t)n / (uint32_t)PSZ;
        const uint32_t off = (uint32_t)n - p * PSZ;
        const float* pr = partials + (size_t)p * GOWN * PROW + off;
        float a8 = 0.f;
        #pragma unroll
        for (int r = 0; r < GOWN; ++r) a8 += pr[(size_t)r * PROW];

        const float4 a  = sf[eidx];
        const float4 b  = sf[16 + ni];
        const float4 c4 = sf[32];
        const float lk  = a.x + b.x + c4.x;
        const float lpn = a.z + b.z + c4.z;
        const float li  = a.w + b.w + c4.w;
        const float pk  = 1.f / (1.f + __expf(-lk));
        const float ppn = 1.f / (1.f + __expf(-lpn));
        const float pi  = 1.f / (1.f + __expf(-li));

        v = pi + sv * (pk + ppn) + a8;
        const float d = target[n] - v;
        sq = d * d;
    }
    sq = wave_reduce(sq);
    __shared__ float wsum[4];
    const int lane = threadIdx.x & 63, wid = threadIdx.x >> 6;
    if (lane == 0) wsum[wid] = sq;
    __syncthreads();
    if (threadIdx.x == 0) {
        float tot = (wsum[0] + wsum[1] + wsum[2] + wsum[3]) * (1.0f / (float)N_EDGES);
        if (blockIdx.x == 0) {
            #pragma unroll
            for (int c = 0; c < 16; ++c) tot += lossp[c * 16] * (1.0f / (float)N_EDGES);
        }
        atomicAdd(loss_out, tot);
    }
    if (active) out[n] = v;
}

// ---------------------------------------------------------------------------
// Fallback path (round-3 verified): per-XCD u32 Q20 atomics / device-scope.
// ---------------------------------------------------------------------------
template<int MODE>
__global__ __launch_bounds__(256) void edge_kernel(
    const float* __restrict__ s,
    const int* __restrict__ src,
    const int* __restrict__ dst,
    const int* __restrict__ brev,
    const uint8_t* __restrict__ ei,
    const uint8_t* __restrict__ nib,
    const float* __restrict__ tabs,
    const float* __restrict__ target,
    uint32_t* __restrict__ acc,
    float* __restrict__ lossp,
    float* __restrict__ out,
    float* __restrict__ loss_out)
{
    __shared__ float4 sf[MODE ? 160 : 33];
    if (threadIdx.x < 33) sf[threadIdx.x] = ((const float4*)tabs)[threadIdx.x];
    __syncthreads();

    int xcc = 0;
    uint32_t* accx = acc;
    if (MODE == 1) {
        xcc  = get_xcc();
        accx = acc + (size_t)xcc * N_NODES;
    }

    const int t = blockIdx.x * blockDim.x + threadIdx.x;
    const bool active = (t < N_NONLOOP / 4);
    float lsum = 0.f;
    float ov[4];
    int   iv[4];
    int   dsv[4];
    int   g = 0;

    if (active) {
        g = (N_NODES / 4) + t;
        const vint4   rv = __builtin_nontemporal_load(&((const vint4*)brev)[g]);
        const vint4   sr = __builtin_nontemporal_load(&((const vint4*)src)[g]);
        const vint4   ds = __builtin_nontemporal_load(&((const vint4*)dst)[g]);
        const vfloat4 sv = __builtin_nontemporal_load(&((const vfloat4*)s)[g]);
        const vfloat4 tg = __builtin_nontemporal_load(&((const vfloat4*)target)[g]);

        const int rvv[4] = {rv.x, rv.y, rv.z, rv.w};
        const int srv[4] = {sr.x, sr.y, sr.z, sr.w};
        dsv[0] = ds.x; dsv[1] = ds.y; dsv[2] = ds.z; dsv[3] = ds.w;
        const float svv[4] = {sv.x, sv.y, sv.z, sv.w};
        const float tgv[4] = {tg.x, tg.y, tg.z, tg.w};

        int   eidx[4], ni[4];
        float ss[4], sd[4];
        #pragma unroll
        for (int j = 0; j < 4; ++j) {
            eidx[j] = ei[rvv[j]];
            ni[j]   = nib[srv[j]];
            ss[j]   = s[srv[j]];
            sd[j]   = s[dsv[j]];
        }

        const float4 c4 = sf[32];
        #pragma unroll
        for (int j = 0; j < 4; ++j) {
            const float4 a = sf[eidx[j]];
            const float4 b = sf[16 + ni[j]];
            const float lk  = a.x + b.x + c4.x;
            const float lp  = a.y + b.y + c4.y;
            const float lpn = a.z + b.z + c4.z;
            const float li  = a.w + b.w + c4.w;
            const float pk  = 1.f / (1.f + __expf(-lk));
            const float pp  = 1.f / (1.f + __expf(-lp));
            const float ppn = 1.f / (1.f + __expf(-lpn));
            const float pi  = 1.f / (1.f + __expf(-li));

            const float s_wo = svv[j] - sd[j];
            const float s_w  = s_wo + ss[j];
            iv[j] = __float2int_rn((pp * s_wo + ppn * s_w) * ACC_SCALE);

            ov[j] = pi + svv[j] * pk;
            const float d = tgv[j] - ov[j];
            lsum += d * d;
        }
    }

    lsum = wave_reduce(lsum);
    __shared__ float wsum[4];
    const int lane = threadIdx.x & 63, wid = threadIdx.x >> 6;
    if (lane == 0) wsum[wid] = lsum;
    __syncthreads();
    if (threadIdx.x == 0) {
        const float tot = (wsum[0] + wsum[1] + wsum[2] + wsum[3]) * (1.0f / (float)N_EDGES);
        if (MODE == 1) l2_atomic_add_f32(&lossp[xcc * 32], tot);
        else           atomicAdd(loss_out, tot);
    }

    if (active) {
        #pragma unroll
        for (int j = 0; j < 4; ++j) {
            if (MODE == 1) l2_atomic_add_u32(&accx[dsv[j]], (uint32_t)iv[j]);
            else           atomicAdd((unsigned int*)&acc[dsv[j]], (unsigned int)iv[j]);
        }
        vfloat4 o4 = {ov[0], ov[1], ov[2], ov[3]};
        __builtin_nontemporal_store(o4, &((vfloat4*)out)[g]);
    }
}

template<int NC>
__global__ __launch_bounds__(256) void finalize_nodes(
    const float* __restrict__ s,
    const int* __restrict__ brev,
    const uint8_t* __restrict__ ei,
    const uint8_t* __restrict__ nib,
    const float* __restrict__ tabs,
    const float* __restrict__ target,
    const uint32_t* __restrict__ acc,
    const float* __restrict__ lossp,
    float* __restrict__ out,
    float* __restrict__ loss_out)
{
    __shared__ float4 sf[33];
    if (threadIdx.x < 33) sf[threadIdx.x] = ((const float4*)tabs)[threadIdx.x];
    __syncthreads();

    const int n = blockIdx.x * blockDim.x + threadIdx.x;
    const bool active = (n < N_NODES);
    float sq = 0.f, v = 0.f;
    if (active) {
        const int  eidx = ei[brev[n]];
        const int  ni   = nib[n];
        const float sv  = s[n];

        uint32_t asum = 0u;
        #pragma unroll
        for (int k = 0; k < NC; ++k) asum += acc[(size_t)k * N_NODES + n];
        const float a8 = (float)(int)asum * ACC_INV;

        const float4 a  = sf[eidx];
        const float4 b  = sf[16 + ni];
        const float4 c4 = sf[32];
        const float lk  = a.x + b.x + c4.x;
        const float lpn = a.z + b.z + c4.z;
        const float li  = a.w + b.w + c4.w;
        const float pk  = 1.f / (1.f + __expf(-lk));
        const float ppn = 1.f / (1.f + __expf(-lpn));
        const float pi  = 1.f / (1.f + __expf(-li));

        v = pi + sv * (pk + ppn) + a8;
        const float d = target[n] - v;
        sq = d * d;
    }
    sq = wave_reduce(sq);
    __shared__ float wsum[4];
    const int lane = threadIdx.x & 63, wid = threadIdx.x >> 6;
    if (lane == 0) wsum[wid] = sq;
    __syncthreads();
    if (threadIdx.x == 0) {
        float tot = (wsum[0] + wsum[1] + wsum[2] + wsum[3]) * (1.0f / (float)N_EDGES);
        if (blockIdx.x == 0) {
            #pragma unroll
            for (int k = 0; k < NXCD; ++k) tot += lossp[k * 32];
        }
        atomicAdd(loss_out, tot);
    }
    if (active) out[n] = v;
}

extern "C" void kernel_launch(void* const* d_in, const int* in_sizes, int n_in,
                              void* d_out, int out_size, void* d_ws, size_t ws_size,
                              hipStream_t stream) {
    const int*   node_states   = (const int*)d_in[0];
    const int*   edge_states   = (const int*)d_in[1];
    const float* scalars       = (const float*)d_in[2];
    const int*   edge_index    = (const int*)d_in[3];
    const int*   brev          = (const int*)d_in[4];
    const float* batch_scalars = (const float*)d_in[5];
    // d_in[6] = processor_step (batch axis-1 size 1 -> index 0)
    const int*   training_step = (const int*)d_in[7];
    const float* node_emb  = (const float*)d_in[8];
    const float* edge_emb  = (const float*)d_in[9];
    const float* combine_W = (const float*)d_in[10];
    const float* combine_b = (const float*)d_in[11];
    const float* keep_W  = (const float*)d_in[12];
    const float* keep_b  = (const float*)d_in[13];
    const float* push_W  = (const float*)d_in[14];
    const float* push_b  = (const float*)d_in[15];
    const float* pushn_W = (const float*)d_in[16];
    const float* pushn_b = (const float*)d_in[17];
    const float* inc_W   = (const float*)d_in[18];
    const float* inc_b   = (const float*)d_in[19];

    float* out = (float*)d_out;  // [0..E) new_scalars, [E] loss

    const int* srcp = edge_index;
    const int* dstp = edge_index + N_EDGES;

    // ---- workspace budgets ----
    const size_t PAIRS_B    = (size_t)NP * PCAP * 8;        // 7,864,320
    const size_t PARTIALS_B = (size_t)NP * GOWN * PROW * 4; // 6,422,528
    const size_t need_binned = 3072 + PAIRS_B + PARTIALS_B + N_EDGES + N_NODES; // ~14.7 MB
    const size_t need_scoped = 2048 + (size_t)NXCD * N_NODES * 4 + N_EDGES + N_NODES; // ~4.3 MB

    char* ws = (char*)d_ws;
    const int ethreads = N_NONLOOP / 4;   // 225000
    const int eblocks  = (ethreads + 255) / 256;

    if (ws_size >= need_binned) {
        // ---- binned (atomic-free accumulation) path ----
        float*    tabs     = (float*)ws;                         // 1 KiB
        float*    lossp    = (float*)(ws + 1024);                // 1 KiB (16 cells x 64B)
        uint32_t* cnt      = (uint32_t*)(ws + 2048);             // 1 KiB pad
        u64*      pairs    = (u64*)(ws + 3072);                  // 7.86 MB
        float*    partials = (float*)(ws + 3072 + PAIRS_B);      // 6.42 MB
        uint8_t*  ei       = (uint8_t*)(ws + 3072 + PAIRS_B + PARTIALS_B);
        uint8_t*  nib      = ei + N_EDGES;

        fused_pre<<<TAB_BLOCKS + NODE_BLOCKS + EI_BLOCKS, 256, 0, stream>>>(
            node_states, edge_states, node_emb, edge_emb,
            combine_W, combine_b, keep_W, keep_b, push_W, push_b,
            pushn_W, pushn_b, inc_W, inc_b, training_step,
            nullptr, cnt, ei, nib, tabs, lossp, out + N_EDGES, 0);

        edge_compact<<<eblocks, 256, 0, stream>>>(
            scalars, srcp, dstp, brev, ei, nib, tabs, batch_scalars,
            cnt, pairs, lossp, out);

        bin_accum<<<NP * GOWN, 256, 0, stream>>>(pairs, cnt, partials);

        finalize_binned<<<(N_NODES + 255) / 256, 256, 0, stream>>>(
            scalars, brev, ei, nib, tabs, batch_scalars, partials, lossp,
            out, out + N_EDGES);
    } else {
        const bool scoped = (ws_size >= need_scoped);
        const int nc = scoped ? NXCD : 1;

        float*    tabs  = (float*)ws;
        float*    lossp = (float*)(ws + 1024);
        uint32_t* acc   = (uint32_t*)(ws + 2048);
        uint8_t*  ei    = (uint8_t*)(ws + 2048 + (size_t)nc * N_NODES * 4);
        uint8_t*  nib   = ei + N_EDGES;

        fused_pre<<<TAB_BLOCKS + NODE_BLOCKS + EI_BLOCKS, 256, 0, stream>>>(
            node_states, edge_states, node_emb, edge_emb,
            combine_W, combine_b, keep_W, keep_b, push_W, push_b,
            pushn_W, pushn_b, inc_W, inc_b, training_step,
            acc, nullptr, ei, nib, tabs, lossp, out + N_EDGES, nc);

        if (scoped) {
            edge_kernel<1><<<eblocks, 256, 0, stream>>>(
                scalars, srcp, dstp, brev, ei, nib, tabs, batch_scalars,
                acc, lossp, out, out + N_EDGES);
            finalize_nodes<NXCD><<<(N_NODES + 255) / 256, 256, 0, stream>>>(
                scalars, brev, ei, nib, tabs, batch_scalars, acc, lossp,
                out, out + N_EDGES);
        } else {
            edge_kernel<0><<<eblocks, 256, 0, stream>>>(
                scalars, srcp, dstp, brev, ei, nib, tabs, batch_scalars,
                acc, lossp, out, out + N_EDGES);
            finalize_nodes<1><<<(N_NODES + 255) / 256, 256, 0, stream>>>(
                scalars, brev, ei, nib, tabs, batch_scalars, acc, lossp,
                out, out + N_EDGES);
        }
    }
}